// Round 1
// baseline (1324.984 us; speedup 1.0000x reference)
//
#include <hip/hip_runtime.h>
#include <cstdint>
#include <cstddef>

#define BB 2
#define NN 8192
#define CC 128
#define KK 16
#define CHN 8
#define CHL (NN / CHN)
#define EPSV 1e-5f

typedef unsigned long long u64;
typedef unsigned int u32;

// ---------------- prep: pack (x,y,z, sq) ----------------
__global__ __launch_bounds__(256) void k_prep(const float* __restrict__ xyz,
                                              float4* __restrict__ xyzw) {
  int t = blockIdx.x * 256 + threadIdx.x;
  if (t >= BB * NN) return;
  float x = xyz[t * 3 + 0], y = xyz[t * 3 + 1], z = xyz[t * 3 + 2];
  float sq = __fadd_rn(__fadd_rn(__fmul_rn(x, x), __fmul_rn(y, y)), __fmul_rn(z, z));
  xyzw[t] = make_float4(x, y, z, sq);
}

// ---------------- KNN pass 1: per-thread top-16 over a candidate chunk ----------------
// Thread = one query; blockIdx.y = candidate chunk (uniform per wave -> scalar loads).
// Key = (f32bits(dist)<<32) | idx : lexicographic (dist, idx) matches top_k stability.
__global__ __launch_bounds__(256) void k_knn1(const float4* __restrict__ xyzw,
                                              u64* __restrict__ cand) {
  const int tid = threadIdx.x;
  const int bx = blockIdx.x;            // 0..(BB*NN/256)-1
  const int ch = blockIdx.y;            // 0..CHN-1
  const int b = bx / (NN / 256);
  const int n = (bx % (NN / 256)) * 256 + tid;
  const float4 q = xyzw[b * NN + n];
  u64 keys[KK];
#pragma unroll
  for (int i = 0; i < KK; ++i) keys[i] = ~0ull;
  const int m0 = ch * CHL;
  for (int mi = 0; mi < CHL; ++mi) {
    const int m = m0 + mi;
    const float4 c = xyzw[b * NN + m];  // wave-uniform address -> s_load
    float dot = __fadd_rn(__fadd_rn(__fmul_rn(q.x, c.x), __fmul_rn(q.y, c.y)),
                          __fmul_rn(q.z, c.z));
    float d = __fsub_rn(__fadd_rn(q.w, c.w), __fmul_rn(2.0f, dot));
    d = fmaxf(d, 0.0f);
    u64 key = ((u64)__float_as_uint(d) << 32) | (u32)m;
    if (key < keys[KK - 1]) {
      keys[KK - 1] = key;
#pragma unroll
      for (int i = KK - 1; i > 0; --i) {
        u64 a = keys[i - 1], bk = keys[i];
        bool sw = bk < a;
        keys[i - 1] = sw ? bk : a;
        keys[i] = sw ? a : bk;
      }
    }
  }
  const int t = b * NN + n;
#pragma unroll
  for (int j = 0; j < KK; ++j) cand[(size_t)(ch * KK + j) * (BB * NN) + t] = keys[j];
}

// ---------------- KNN pass 2: merge 8 chunk top-16s -> final top-16 ----------------
__global__ __launch_bounds__(256) void k_knn2(const u64* __restrict__ cand,
                                              int* __restrict__ idx) {
  int t = blockIdx.x * 256 + threadIdx.x;
  if (t >= BB * NN) return;
  u64 best[KK];
#pragma unroll
  for (int i = 0; i < KK; ++i) best[i] = ~0ull;
  for (int i = 0; i < CHN * KK; ++i) {
    u64 k = cand[(size_t)i * (BB * NN) + t];
    if (k < best[KK - 1]) {
      best[KK - 1] = k;
#pragma unroll
      for (int q = KK - 1; q > 0; --q) {
        u64 a = best[q - 1], bb = best[q];
        bool sw = bb < a;
        best[q - 1] = sw ? bb : a;
        best[q] = sw ? a : bb;
      }
    }
  }
#pragma unroll
  for (int j = 0; j < KK; ++j) idx[t * KK + j] = (int)(best[j] & 0xffffffffu);
}

// ---------------- generic fp32 GEMM: C[M,128] = A[M,128] @ W[128,128]^T (+epilogue) ----
// EPI: 0 = none, 1 = +bias, 2 = +bias -> BN -> ReLU
// W staged in LDS with XOR swizzle on the k index (avoids 32-way bank conflict).
template <int EPI>
__global__ __launch_bounds__(256) void k_gemm(const float* __restrict__ A,
                                              const float* __restrict__ W,
                                              const float* __restrict__ bias,
                                              const float* __restrict__ g,
                                              const float* __restrict__ bet,
                                              const float* __restrict__ mean,
                                              const float* __restrict__ var,
                                              float* __restrict__ C) {
  __shared__ float Wl[128 * 128];
  const int tid = threadIdx.x;
  const int r0base = blockIdx.x * 64;
  const float4* W4 = (const float4*)W;
#pragma unroll
  for (int i = 0; i < 16; ++i) {
    int f = i * 256 + tid;  // float4 index 0..4095
    int c = f >> 5;
    int k4 = f & 31;
    float4 w = W4[f];
    *(float4*)&Wl[c * 128 + ((k4 * 4) ^ ((c & 7) << 2))] = w;
  }
  __syncthreads();
  const int rowgrp = tid >> 5;   // 0..7
  const int colgrp = tid & 31;   // 0..31 ; cols = colgrp + 32*ci (strided)
  const int rbase = r0base + rowgrp * 8;
  float acc[8][4];
#pragma unroll
  for (int j = 0; j < 8; ++j)
#pragma unroll
    for (int ci = 0; ci < 4; ++ci) acc[j][ci] = 0.f;

  for (int k4 = 0; k4 < 32; ++k4) {
    float4 a4[8];
#pragma unroll
    for (int j = 0; j < 8; ++j)
      a4[j] = *(const float4*)&A[(size_t)(rbase + j) * 128 + k4 * 4];
    float4 w4[4];
#pragma unroll
    for (int ci = 0; ci < 4; ++ci) {
      int c = colgrp + 32 * ci;
      w4[ci] = *(const float4*)&Wl[c * 128 + ((k4 * 4) ^ ((c & 7) << 2))];
    }
#pragma unroll
    for (int j = 0; j < 8; ++j)
#pragma unroll
      for (int ci = 0; ci < 4; ++ci) {
        acc[j][ci] = fmaf(a4[j].x, w4[ci].x, acc[j][ci]);
        acc[j][ci] = fmaf(a4[j].y, w4[ci].y, acc[j][ci]);
        acc[j][ci] = fmaf(a4[j].z, w4[ci].z, acc[j][ci]);
        acc[j][ci] = fmaf(a4[j].w, w4[ci].w, acc[j][ci]);
      }
  }
#pragma unroll
  for (int ci = 0; ci < 4; ++ci) {
    const int c = colgrp + 32 * ci;
    float bv = (EPI >= 1) ? bias[c] : 0.f;
    float rr = 0.f, gg = 0.f, mn = 0.f, bt = 0.f;
    if (EPI == 2) {
      rr = 1.0f / sqrtf(var[c] + EPSV);
      gg = g[c];
      mn = mean[c];
      bt = bet[c];
    }
#pragma unroll
    for (int j = 0; j < 8; ++j) {
      float v = acc[j][ci] + bv;
      if (EPI == 2) v = fmaxf(((v - mn) * rr) * gg + bt, 0.f);
      C[(size_t)(rbase + j) * 128 + c] = v;
    }
  }
}

// ---------------- pos-MLP hidden: h1 = relu(BN(pW1 @ rel + pb1)) ----------------
__global__ __launch_bounds__(256) void k_h1(const float4* __restrict__ xyzw,
                                            const int* __restrict__ idx,
                                            const float* __restrict__ pW1,
                                            const float* __restrict__ pb1,
                                            const float* __restrict__ pg,
                                            const float* __restrict__ pbeta,
                                            const float* __restrict__ pm,
                                            const float* __restrict__ pv,
                                            float* __restrict__ X, int q0) {
  const int tid = threadIdx.x;
  const int r = blockIdx.x * 2 + (tid >> 7);  // local pair row
  const int c = tid & 127;
  const int qi = q0 + (r >> 4);
  const int j = r & 15;
  const int m = idx[qi * KK + j];
  const int base = (qi / NN) * NN;
  float4 pn = xyzw[qi];
  float4 pmm = xyzw[base + m];
  float rx = pmm.x - pn.x, ry = pmm.y - pn.y, rz = pmm.z - pn.z;
  float h = pW1[c * 3 + 0] * rx + pW1[c * 3 + 1] * ry + pW1[c * 3 + 2] * rz + pb1[c];
  float rr = 1.0f / sqrtf(pv[c] + EPSV);
  h = ((h - pm[c]) * rr) * pg[c] + pbeta[c];
  X[(size_t)r * 128 + c] = fmaxf(h, 0.f);
}

// ---------------- u = q - k_gather + pos ----------------
__global__ __launch_bounds__(256) void k_u(const float* __restrict__ qb,
                                           const float* __restrict__ kb,
                                           const float* __restrict__ Y,
                                           const int* __restrict__ idx,
                                           float* __restrict__ X, int q0) {
  const int tid = threadIdx.x;
  const int r = blockIdx.x * 2 + (tid >> 7);
  const int c = tid & 127;
  const int qi = q0 + (r >> 4);
  const int j = r & 15;
  const int m = idx[qi * KK + j];
  const int mrow = (qi / NN) * NN + m;
  X[(size_t)r * 128 + c] =
      qb[(size_t)qi * 128 + c] - kb[(size_t)mrow * 128 + c] + Y[(size_t)r * 128 + c];
}

// ---------------- softmax over K (per channel) + combine ----------------
__global__ __launch_bounds__(256) void k_sm(const float* __restrict__ X,
                                            const float* __restrict__ Y,
                                            const float* __restrict__ vb,
                                            const int* __restrict__ idx,
                                            float* __restrict__ outb, int q0) {
  const int tid = threadIdx.x;
  const int ql = blockIdx.x * 2 + (tid >> 7);
  const int c = tid & 127;
  const int qi = q0 + ql;
  const int base = (qi / NN) * NN;
  float av[KK], pvv[KK], vv[KK];
#pragma unroll
  for (int j = 0; j < KK; ++j) {
    av[j] = X[(size_t)(ql * KK + j) * 128 + c];
    pvv[j] = Y[(size_t)(ql * KK + j) * 128 + c];
    int m = idx[qi * KK + j];
    vv[j] = vb[(size_t)(base + m) * 128 + c];
  }
  float mx = av[0];
#pragma unroll
  for (int j = 1; j < KK; ++j) mx = fmaxf(mx, av[j]);
  float e[KK], s = 0.f;
#pragma unroll
  for (int j = 0; j < KK; ++j) {
    e[j] = expf(av[j] - mx);
    s += e[j];
  }
  float inv = 1.0f / s;
  float o = 0.f;
#pragma unroll
  for (int j = 0; j < KK; ++j) o += (e[j] * inv) * (vv[j] + pvv[j]);
  outb[(size_t)qi * 128 + c] = o;
}

// ---------------- host launch ----------------
extern "C" void kernel_launch(void* const* d_in, const int* in_sizes, int n_in,
                              void* d_out, int out_size, void* d_ws, size_t ws_size,
                              hipStream_t stream) {
  const float* xyz = (const float*)d_in[0];
  const float* feat = (const float*)d_in[1];
  const float* Wq = (const float*)d_in[2];
  const float* Wk = (const float*)d_in[3];
  const float* Wv = (const float*)d_in[4];
  const float* pW1 = (const float*)d_in[5];
  const float* pb1 = (const float*)d_in[6];
  const float* pg = (const float*)d_in[7];
  const float* pbeta = (const float*)d_in[8];
  const float* pmean = (const float*)d_in[9];
  const float* pvar = (const float*)d_in[10];
  const float* pW2 = (const float*)d_in[11];
  const float* pb2 = (const float*)d_in[12];
  const float* aW1 = (const float*)d_in[13];
  const float* ab1 = (const float*)d_in[14];
  const float* ag = (const float*)d_in[15];
  const float* abeta = (const float*)d_in[16];
  const float* amean = (const float*)d_in[17];
  const float* avar = (const float*)d_in[18];
  const float* aW2 = (const float*)d_in[19];
  const float* ab2 = (const float*)d_in[20];
  const float* Wout = (const float*)d_in[21];
  float* out = (float*)d_out;
  char* ws = (char*)d_ws;

  size_t off = 0;
  auto alloc = [&](size_t bytes) {
    size_t r = off;
    off += (bytes + 255) & ~(size_t)255;
    return r;
  };
  float4* xyzw = (float4*)(ws + alloc((size_t)BB * NN * 16));
  int* idx = (int*)(ws + alloc((size_t)BB * NN * KK * 4));
  size_t o_qb = alloc((size_t)BB * NN * CC * 4);
  size_t o_kb = alloc((size_t)BB * NN * CC * 4);
  size_t o_vb = alloc((size_t)BB * NN * CC * 4);
  size_t o_ob = alloc((size_t)BB * NN * CC * 4);
  float* qb = (float*)(ws + o_qb);
  float* kb = (float*)(ws + o_kb);
  float* vb = (float*)(ws + o_vb);
  float* outb = (float*)(ws + o_ob);
  // KNN candidate buffer (16 MB) aliases qb+kb (dead until after k_knn2).
  u64* cand = (u64*)(ws + o_qb);

  size_t rem = (ws_size > off) ? (ws_size - off) : 0;
  int chunks = 64;
  const int opts[7] = {1, 2, 4, 8, 16, 32, 64};
  for (int i = 0; i < 7; ++i) {
    size_t xb = (size_t)(BB * NN / opts[i]) * KK * CC * 4;
    if (3 * xb <= rem) { chunks = opts[i]; break; }
  }
  const size_t xb = (size_t)(BB * NN / chunks) * KK * CC * 4;
  float* X = (float*)(ws + off);
  float* Y = (float*)(ws + off + xb);
  float* Z = (float*)(ws + off + 2 * xb);

  const int QC = BB * NN / chunks;
  const int rows = QC * KK;

  k_prep<<<(BB * NN) / 256, 256, 0, stream>>>(xyz, xyzw);
  k_knn1<<<dim3((BB * NN) / 256, CHN), 256, 0, stream>>>(xyzw, cand);
  k_knn2<<<(BB * NN) / 256, 256, 0, stream>>>(cand, idx);

  k_gemm<0><<<(BB * NN) / 64, 256, 0, stream>>>(feat, Wq, nullptr, nullptr, nullptr,
                                                nullptr, nullptr, qb);
  k_gemm<0><<<(BB * NN) / 64, 256, 0, stream>>>(feat, Wk, nullptr, nullptr, nullptr,
                                                nullptr, nullptr, kb);
  k_gemm<0><<<(BB * NN) / 64, 256, 0, stream>>>(feat, Wv, nullptr, nullptr, nullptr,
                                                nullptr, nullptr, vb);

  for (int cc = 0; cc < chunks; ++cc) {
    const int q0 = cc * QC;
    k_h1<<<rows / 2, 256, 0, stream>>>(xyzw, idx, pW1, pb1, pg, pbeta, pmean, pvar, X, q0);
    k_gemm<1><<<rows / 64, 256, 0, stream>>>(X, pW2, pb2, nullptr, nullptr, nullptr,
                                             nullptr, Y);
    k_u<<<rows / 2, 256, 0, stream>>>(qb, kb, Y, idx, X, q0);
    k_gemm<2><<<rows / 64, 256, 0, stream>>>(X, aW1, ab1, ag, abeta, amean, avar, Z);
    k_gemm<1><<<rows / 64, 256, 0, stream>>>(Z, aW2, ab2, nullptr, nullptr, nullptr,
                                             nullptr, X);
    k_sm<<<QC / 2, 256, 0, stream>>>(X, Y, vb, idx, outb, q0);
  }

  k_gemm<0><<<(BB * NN) / 64, 256, 0, stream>>>(outb, Wout, nullptr, nullptr, nullptr,
                                                nullptr, nullptr, out);
}

// Round 2
// 831.926 us; speedup vs baseline: 1.5927x; 1.5927x over previous
//
#include <hip/hip_runtime.h>
#include <cstdint>
#include <cstddef>

#define BB 2
#define NN 8192
#define CC 128
#define KK 16
#define CHN 16
#define CHL (NN / CHN)
#define EPSV 1e-5f

typedef unsigned long long u64;
typedef unsigned int u32;

// ---------------- prep: pack (x,y,z, sq) ----------------
__global__ __launch_bounds__(256) void k_prep(const float* __restrict__ xyz,
                                              float4* __restrict__ xyzw) {
  int t = blockIdx.x * 256 + threadIdx.x;
  if (t >= BB * NN) return;
  float x = xyz[t * 3 + 0], y = xyz[t * 3 + 1], z = xyz[t * 3 + 2];
  float sq = __fadd_rn(__fadd_rn(__fmul_rn(x, x), __fmul_rn(y, y)), __fmul_rn(z, z));
  xyzw[t] = make_float4(x, y, z, sq);
}

// ---------------- KNN pass 1 ----------------
// Key = (f32bits(dist)<<32)|idx reinterpreted as a positive finite double:
// ordering of positive doubles == ordering of u64 bit patterns, so sorted
// insert = 16 x (v_min_f64 + v_max_f64), branchless-correct.
__global__ __launch_bounds__(256) void k_knn1(const float4* __restrict__ xyzw,
                                              u64* __restrict__ cand) {
  __shared__ float4 pts[CHL];
  const int tid = threadIdx.x;
  const int bx = blockIdx.x;            // 0..(BB*NN/256)-1
  const int ch = blockIdx.y;            // 0..CHN-1
  const int b = bx / (NN / 256);
  const int n = (bx % (NN / 256)) * 256 + tid;
  const int m0 = ch * CHL;
  for (int i = tid; i < CHL; i += 256) pts[i] = xyzw[b * NN + m0 + i];
  const float4 q = xyzw[b * NN + n];
  __syncthreads();
  double keys[KK];
#pragma unroll
  for (int i = 0; i < KK; ++i) keys[i] = __longlong_as_double(0x7FEFFFFFFFFFFFFFLL);
#pragma unroll 2
  for (int mi = 0; mi < CHL; ++mi) {
    const float4 c = pts[mi];
    float dot = __fadd_rn(__fadd_rn(__fmul_rn(q.x, c.x), __fmul_rn(q.y, c.y)),
                          __fmul_rn(q.z, c.z));
    float d = __fsub_rn(__fadd_rn(q.w, c.w), __fmul_rn(2.0f, dot));
    d = fmaxf(d, 0.0f);
    u64 kb_ = ((u64)__float_as_uint(d) << 32) | (u32)(m0 + mi);
    double kd = __longlong_as_double((long long)kb_);
    if (kd < keys[KK - 1]) {
#pragma unroll
      for (int i = 0; i < KK; ++i) {
        double lo = fmin(keys[i], kd);
        kd = fmax(keys[i], kd);
        keys[i] = lo;
      }
    }
  }
  const int t = b * NN + n;
#pragma unroll
  for (int j = 0; j < KK; ++j)
    cand[(size_t)(ch * KK + j) * (BB * NN) + t] = (u64)__double_as_longlong(keys[j]);
}

// ---------------- KNN pass 2: merge CHN chunk top-16s ----------------
__global__ __launch_bounds__(256) void k_knn2(const u64* __restrict__ cand,
                                              int* __restrict__ idx) {
  int t = blockIdx.x * 256 + threadIdx.x;
  if (t >= BB * NN) return;
  double best[KK];
#pragma unroll
  for (int i = 0; i < KK; ++i) best[i] = __longlong_as_double(0x7FEFFFFFFFFFFFFFLL);
  for (int i = 0; i < CHN * KK; ++i) {
    double kd = __longlong_as_double((long long)cand[(size_t)i * (BB * NN) + t]);
    if (kd < best[KK - 1]) {
#pragma unroll
      for (int q = 0; q < KK; ++q) {
        double lo = fmin(best[q], kd);
        kd = fmax(best[q], kd);
        best[q] = lo;
      }
    }
  }
#pragma unroll
  for (int j = 0; j < KK; ++j)
    idx[t * KK + j] = (int)((u64)__double_as_longlong(best[j]) & 0xffffffffu);
}

// ---------------- generic fp32 GEMM: C[M,128] = A[M,128] @ W^T ----------------
template <int EPI>
__global__ __launch_bounds__(256) void k_gemm(const float* __restrict__ A,
                                              const float* __restrict__ W,
                                              float* __restrict__ C) {
  __shared__ float Wl[128 * 128];
  const int tid = threadIdx.x;
  const int r0base = blockIdx.x * 64;
  const float4* W4 = (const float4*)W;
#pragma unroll
  for (int i = 0; i < 16; ++i) {
    int f = i * 256 + tid;
    int c = f >> 5;
    int k4 = f & 31;
    *(float4*)&Wl[c * 128 + ((k4 * 4) ^ ((c & 7) << 2))] = W4[f];
  }
  __syncthreads();
  const int rowgrp = tid >> 5;
  const int colgrp = tid & 31;
  const int rbase = r0base + rowgrp * 8;
  float acc[8][4];
#pragma unroll
  for (int j = 0; j < 8; ++j)
#pragma unroll
    for (int ci = 0; ci < 4; ++ci) acc[j][ci] = 0.f;
  for (int k4 = 0; k4 < 32; ++k4) {
    float4 a4[8];
#pragma unroll
    for (int j = 0; j < 8; ++j)
      a4[j] = *(const float4*)&A[(size_t)(rbase + j) * 128 + k4 * 4];
    float4 w4[4];
#pragma unroll
    for (int ci = 0; ci < 4; ++ci) {
      int c = colgrp + 32 * ci;
      w4[ci] = *(const float4*)&Wl[c * 128 + ((k4 * 4) ^ ((c & 7) << 2))];
    }
#pragma unroll
    for (int j = 0; j < 8; ++j)
#pragma unroll
      for (int ci = 0; ci < 4; ++ci) {
        acc[j][ci] = fmaf(a4[j].x, w4[ci].x, acc[j][ci]);
        acc[j][ci] = fmaf(a4[j].y, w4[ci].y, acc[j][ci]);
        acc[j][ci] = fmaf(a4[j].z, w4[ci].z, acc[j][ci]);
        acc[j][ci] = fmaf(a4[j].w, w4[ci].w, acc[j][ci]);
      }
  }
#pragma unroll
  for (int ci = 0; ci < 4; ++ci) {
    const int c = colgrp + 32 * ci;
#pragma unroll
    for (int j = 0; j < 8; ++j) C[(size_t)(rbase + j) * 128 + c] = acc[j][ci];
  }
}

// ---------------- F1: Y = (relu(BN(rel@pW1^T+pb1))) @ pW2^T + pb2 ----------------
// 32 rows/block; h1 tile built in LDS (never hits HBM).
__global__ __launch_bounds__(256) void k_f1(const float4* __restrict__ xyzw,
                                            const int* __restrict__ idx,
                                            const float* __restrict__ pW1,
                                            const float* __restrict__ pb1,
                                            const float* __restrict__ pg,
                                            const float* __restrict__ pbeta,
                                            const float* __restrict__ pm,
                                            const float* __restrict__ pv,
                                            const float* __restrict__ W,
                                            const float* __restrict__ bias,
                                            float* __restrict__ Y, int q0) {
  __shared__ float Wl[128 * 128];
  __shared__ float Al[32 * 128];
  const int tid = threadIdx.x;
  const float4* W4 = (const float4*)W;
#pragma unroll
  for (int i = 0; i < 16; ++i) {
    int f = i * 256 + tid;
    int c = f >> 5;
    int k4 = f & 31;
    *(float4*)&Wl[c * 128 + ((k4 * 4) ^ ((c & 7) << 2))] = W4[f];
  }
  const int R0 = blockIdx.x * 32;
  const int col = tid & 127;
  const float w1x = pW1[col * 3 + 0], w1y = pW1[col * 3 + 1], w1z = pW1[col * 3 + 2];
  const float rr_ = 1.0f / sqrtf(pv[col] + EPSV);
  const float gg_ = pg[col], mn_ = pm[col], bt_ = pbeta[col], b1_ = pb1[col];
#pragma unroll
  for (int i = 0; i < 16; ++i) {
    int row = (tid >> 7) + 2 * i;
    int rr = R0 + row;
    int qi = q0 + (rr >> 4);
    int m = idx[qi * KK + (rr & 15)];
    int base = (qi / NN) * NN;
    float4 pn = xyzw[qi];
    float4 pmm = xyzw[base + m];
    float h = w1x * (pmm.x - pn.x) + w1y * (pmm.y - pn.y) + w1z * (pmm.z - pn.z) + b1_;
    h = ((h - mn_) * rr_) * gg_ + bt_;
    Al[row * 128 + col] = fmaxf(h, 0.f);
  }
  __syncthreads();
  const int rowg = tid >> 5;
  const int colg = tid & 31;
  float acc[4][4];
#pragma unroll
  for (int j = 0; j < 4; ++j)
#pragma unroll
    for (int ci = 0; ci < 4; ++ci) acc[j][ci] = 0.f;
  for (int k4 = 0; k4 < 32; ++k4) {
    float4 a4[4];
#pragma unroll
    for (int j = 0; j < 4; ++j) a4[j] = *(const float4*)&Al[(rowg * 4 + j) * 128 + k4 * 4];
    float4 w4[4];
#pragma unroll
    for (int ci = 0; ci < 4; ++ci) {
      int c = colg + 32 * ci;
      w4[ci] = *(const float4*)&Wl[c * 128 + ((k4 * 4) ^ ((c & 7) << 2))];
    }
#pragma unroll
    for (int j = 0; j < 4; ++j)
#pragma unroll
      for (int ci = 0; ci < 4; ++ci) {
        acc[j][ci] = fmaf(a4[j].x, w4[ci].x, acc[j][ci]);
        acc[j][ci] = fmaf(a4[j].y, w4[ci].y, acc[j][ci]);
        acc[j][ci] = fmaf(a4[j].z, w4[ci].z, acc[j][ci]);
        acc[j][ci] = fmaf(a4[j].w, w4[ci].w, acc[j][ci]);
      }
  }
#pragma unroll
  for (int ci = 0; ci < 4; ++ci) {
    const int c = colg + 32 * ci;
    const float bv = bias[c];
#pragma unroll
    for (int j = 0; j < 4; ++j)
      Y[(size_t)(R0 + rowg * 4 + j) * 128 + c] = acc[j][ci] + bv;
  }
}

// ---------------- F2: Z = relu(BN((q - k_gather + Y) @ aW1^T + ab1)) ----------------
__global__ __launch_bounds__(256) void k_f2(const float* __restrict__ qb,
                                            const float* __restrict__ kb,
                                            const float* __restrict__ Yb,
                                            const int* __restrict__ idx,
                                            const float* __restrict__ W,
                                            const float* __restrict__ bias,
                                            const float* __restrict__ g,
                                            const float* __restrict__ bet,
                                            const float* __restrict__ mean,
                                            const float* __restrict__ var,
                                            float* __restrict__ Z, int q0) {
  __shared__ float Wl[128 * 128];
  __shared__ float Al[32 * 128];
  const int tid = threadIdx.x;
  const float4* W4 = (const float4*)W;
#pragma unroll
  for (int i = 0; i < 16; ++i) {
    int f = i * 256 + tid;
    int c = f >> 5;
    int k4 = f & 31;
    *(float4*)&Wl[c * 128 + ((k4 * 4) ^ ((c & 7) << 2))] = W4[f];
  }
  const int R0 = blockIdx.x * 32;
  const int col = tid & 127;
#pragma unroll
  for (int i = 0; i < 16; ++i) {
    int row = (tid >> 7) + 2 * i;
    int rr = R0 + row;
    int qi = q0 + (rr >> 4);
    int m = idx[qi * KK + (rr & 15)];
    int base = (qi / NN) * NN;
    Al[row * 128 + col] = qb[(size_t)qi * 128 + col] - kb[(size_t)(base + m) * 128 + col] +
                          Yb[(size_t)rr * 128 + col];
  }
  __syncthreads();
  const int rowg = tid >> 5;
  const int colg = tid & 31;
  float acc[4][4];
#pragma unroll
  for (int j = 0; j < 4; ++j)
#pragma unroll
    for (int ci = 0; ci < 4; ++ci) acc[j][ci] = 0.f;
  for (int k4 = 0; k4 < 32; ++k4) {
    float4 a4[4];
#pragma unroll
    for (int j = 0; j < 4; ++j) a4[j] = *(const float4*)&Al[(rowg * 4 + j) * 128 + k4 * 4];
    float4 w4[4];
#pragma unroll
    for (int ci = 0; ci < 4; ++ci) {
      int c = colg + 32 * ci;
      w4[ci] = *(const float4*)&Wl[c * 128 + ((k4 * 4) ^ ((c & 7) << 2))];
    }
#pragma unroll
    for (int j = 0; j < 4; ++j)
#pragma unroll
      for (int ci = 0; ci < 4; ++ci) {
        acc[j][ci] = fmaf(a4[j].x, w4[ci].x, acc[j][ci]);
        acc[j][ci] = fmaf(a4[j].y, w4[ci].y, acc[j][ci]);
        acc[j][ci] = fmaf(a4[j].z, w4[ci].z, acc[j][ci]);
        acc[j][ci] = fmaf(a4[j].w, w4[ci].w, acc[j][ci]);
      }
  }
#pragma unroll
  for (int ci = 0; ci < 4; ++ci) {
    const int c = colg + 32 * ci;
    const float bv = bias[c];
    const float rr2 = 1.0f / sqrtf(var[c] + EPSV);
    const float gg = g[c], mn = mean[c], bt = bet[c];
#pragma unroll
    for (int j = 0; j < 4; ++j) {
      float v = acc[j][ci] + bv;
      v = fmaxf(((v - mn) * rr2) * gg + bt, 0.f);
      Z[(size_t)(R0 + rowg * 4 + j) * 128 + c] = v;
    }
  }
}

// ---------------- F3: X2 = Z @ aW2^T + ab2 ; softmax over K; combine ----------------
__global__ __launch_bounds__(256) void k_f3(const float* __restrict__ Z,
                                            const float* __restrict__ W,
                                            const float* __restrict__ bias,
                                            const float* __restrict__ Yb,
                                            const float* __restrict__ vb,
                                            const int* __restrict__ idx,
                                            float* __restrict__ outb, int q0) {
  __shared__ float Wl[128 * 128];
  const int tid = threadIdx.x;
  const int R0 = blockIdx.x * 64;
  const float4* W4 = (const float4*)W;
#pragma unroll
  for (int i = 0; i < 16; ++i) {
    int f = i * 256 + tid;
    int c = f >> 5;
    int k4 = f & 31;
    *(float4*)&Wl[c * 128 + ((k4 * 4) ^ ((c & 7) << 2))] = W4[f];
  }
  __syncthreads();
  const int rowg = tid >> 5;
  const int colg = tid & 31;
  const int rbase = R0 + rowg * 8;
  float acc[8][4];
#pragma unroll
  for (int j = 0; j < 8; ++j)
#pragma unroll
    for (int ci = 0; ci < 4; ++ci) acc[j][ci] = 0.f;
  for (int k4 = 0; k4 < 32; ++k4) {
    float4 a4[8];
#pragma unroll
    for (int j = 0; j < 8; ++j)
      a4[j] = *(const float4*)&Z[(size_t)(rbase + j) * 128 + k4 * 4];
    float4 w4[4];
#pragma unroll
    for (int ci = 0; ci < 4; ++ci) {
      int c = colg + 32 * ci;
      w4[ci] = *(const float4*)&Wl[c * 128 + ((k4 * 4) ^ ((c & 7) << 2))];
    }
#pragma unroll
    for (int j = 0; j < 8; ++j)
#pragma unroll
      for (int ci = 0; ci < 4; ++ci) {
        acc[j][ci] = fmaf(a4[j].x, w4[ci].x, acc[j][ci]);
        acc[j][ci] = fmaf(a4[j].y, w4[ci].y, acc[j][ci]);
        acc[j][ci] = fmaf(a4[j].z, w4[ci].z, acc[j][ci]);
        acc[j][ci] = fmaf(a4[j].w, w4[ci].w, acc[j][ci]);
      }
  }
  int mrow[8];
#pragma unroll
  for (int j = 0; j < 8; ++j) {
    int rr = rbase + j;
    int qi = q0 + (rr >> 4);
    mrow[j] = (qi / NN) * NN + idx[qi * KK + (rr & 15)];
  }
  const int qout = q0 + (rbase >> 4);
#pragma unroll
  for (int ci = 0; ci < 4; ++ci) {
    const int c = colg + 32 * ci;
    const float bv = bias[c];
    float x[8];
    float mx = -1e30f;
#pragma unroll
    for (int j = 0; j < 8; ++j) {
      x[j] = acc[j][ci] + bv;
      mx = fmaxf(mx, x[j]);
    }
    mx = fmaxf(mx, __shfl_xor(mx, 32));
    float s = 0.f;
#pragma unroll
    for (int j = 0; j < 8; ++j) {
      x[j] = expf(x[j] - mx);
      s += x[j];
    }
    s += __shfl_xor(s, 32);
    float o = 0.f;
#pragma unroll
    for (int j = 0; j < 8; ++j) {
      int rr = rbase + j;
      float pv_ = Yb[(size_t)rr * 128 + c];
      float vv = vb[(size_t)mrow[j] * 128 + c];
      o += x[j] * (vv + pv_);
    }
    o += __shfl_xor(o, 32);
    o *= 1.0f / s;
    if ((rowg & 1) == 0) outb[(size_t)qout * 128 + c] = o;
  }
}

// ---------------- host launch ----------------
extern "C" void kernel_launch(void* const* d_in, const int* in_sizes, int n_in,
                              void* d_out, int out_size, void* d_ws, size_t ws_size,
                              hipStream_t stream) {
  const float* xyz = (const float*)d_in[0];
  const float* feat = (const float*)d_in[1];
  const float* Wq = (const float*)d_in[2];
  const float* Wk = (const float*)d_in[3];
  const float* Wv = (const float*)d_in[4];
  const float* pW1 = (const float*)d_in[5];
  const float* pb1 = (const float*)d_in[6];
  const float* pg = (const float*)d_in[7];
  const float* pbeta = (const float*)d_in[8];
  const float* pmean = (const float*)d_in[9];
  const float* pvar = (const float*)d_in[10];
  const float* pW2 = (const float*)d_in[11];
  const float* pb2 = (const float*)d_in[12];
  const float* aW1 = (const float*)d_in[13];
  const float* ab1 = (const float*)d_in[14];
  const float* ag = (const float*)d_in[15];
  const float* abeta = (const float*)d_in[16];
  const float* amean = (const float*)d_in[17];
  const float* avar = (const float*)d_in[18];
  const float* aW2 = (const float*)d_in[19];
  const float* ab2 = (const float*)d_in[20];
  const float* Wout = (const float*)d_in[21];
  float* out = (float*)d_out;
  char* ws = (char*)d_ws;

  size_t off = 0;
  auto alloc = [&](size_t bytes) {
    size_t r = off;
    off += (bytes + 255) & ~(size_t)255;
    return r;
  };
  float4* xyzw = (float4*)(ws + alloc((size_t)BB * NN * 16));
  int* idx = (int*)(ws + alloc((size_t)BB * NN * KK * 4));
  size_t o_qb = alloc((size_t)BB * NN * CC * 4);
  size_t o_kb = alloc((size_t)BB * NN * CC * 4);
  size_t o_vb = alloc((size_t)BB * NN * CC * 4);
  size_t o_ob = alloc((size_t)BB * NN * CC * 4);
  float* qb = (float*)(ws + o_qb);
  float* kb = (float*)(ws + o_kb);
  float* vb = (float*)(ws + o_vb);
  float* outb = (float*)(ws + o_ob);
  // KNN candidate buffer (CHN*KK*BB*NN*8 = 32 MB) aliases qb..outb (dead then).
  u64* cand = (u64*)(ws + o_qb);

  size_t rem = (ws_size > off) ? (ws_size - off) : 0;
  int chunks = 64;
  const int opts[7] = {1, 2, 4, 8, 16, 32, 64};
  for (int i = 0; i < 7; ++i) {
    size_t xb = (size_t)(BB * NN / opts[i]) * KK * CC * 4;
    if (2 * xb <= rem) { chunks = opts[i]; break; }
  }
  const size_t xb = (size_t)(BB * NN / chunks) * KK * CC * 4;
  float* Y = (float*)(ws + off);
  float* Zb = (float*)(ws + off + xb);

  const int QC = BB * NN / chunks;
  const int rows = QC * KK;

  k_prep<<<(BB * NN) / 256, 256, 0, stream>>>(xyz, xyzw);
  k_knn1<<<dim3((BB * NN) / 256, CHN), 256, 0, stream>>>(xyzw, cand);
  k_knn2<<<(BB * NN) / 256, 256, 0, stream>>>(cand, idx);

  k_gemm<0><<<(BB * NN) / 64, 256, 0, stream>>>(feat, Wq, qb);
  k_gemm<0><<<(BB * NN) / 64, 256, 0, stream>>>(feat, Wk, kb);
  k_gemm<0><<<(BB * NN) / 64, 256, 0, stream>>>(feat, Wv, vb);

  for (int cc = 0; cc < chunks; ++cc) {
    const int q0 = cc * QC;
    k_f1<<<rows / 32, 256, 0, stream>>>(xyzw, idx, pW1, pb1, pg, pbeta, pmean, pvar,
                                        pW2, pb2, Y, q0);
    k_f2<<<rows / 32, 256, 0, stream>>>(qb, kb, Y, idx, aW1, ab1, ag, abeta, amean,
                                        avar, Zb, q0);
    k_f3<<<rows / 64, 256, 0, stream>>>(Zb, aW2, ab2, Y, vb, idx, outb, q0);
  }

  k_gemm<0><<<(BB * NN) / 64, 256, 0, stream>>>(outb, Wout, out);
}

// Round 3
// 530.206 us; speedup vs baseline: 2.4990x; 1.5691x over previous
//
#include <hip/hip_runtime.h>
#include <cstdint>
#include <cstddef>

#define BB 2
#define NN 8192
#define CC 128
#define KK 16
#define CHN 16
#define CHL (NN / CHN)
#define EPSV 1e-5f

typedef unsigned long long u64;
typedef unsigned int u32;
typedef unsigned short ushort_t;
typedef short short8v __attribute__((ext_vector_type(8)));
typedef float f32x4 __attribute__((ext_vector_type(4)));

// ---------------- prep: pack (x,y,z, sq) ----------------
__global__ __launch_bounds__(256) void k_prep(const float* __restrict__ xyz,
                                              float4* __restrict__ xyzw) {
  int t = blockIdx.x * 256 + threadIdx.x;
  if (t >= BB * NN) return;
  float x = xyz[t * 3 + 0], y = xyz[t * 3 + 1], z = xyz[t * 3 + 2];
  float sq = __fadd_rn(__fadd_rn(__fmul_rn(x, x), __fmul_rn(y, y)), __fmul_rn(z, z));
  xyzw[t] = make_float4(x, y, z, sq);
}

// ---------------- KNN pass 1 (unchanged from R2) ----------------
__global__ __launch_bounds__(256) void k_knn1(const float4* __restrict__ xyzw,
                                              u64* __restrict__ cand) {
  __shared__ float4 pts[CHL];
  const int tid = threadIdx.x;
  const int bx = blockIdx.x;
  const int ch = blockIdx.y;
  const int b = bx / (NN / 256);
  const int n = (bx % (NN / 256)) * 256 + tid;
  const int m0 = ch * CHL;
  for (int i = tid; i < CHL; i += 256) pts[i] = xyzw[b * NN + m0 + i];
  const float4 q = xyzw[b * NN + n];
  __syncthreads();
  double keys[KK];
#pragma unroll
  for (int i = 0; i < KK; ++i) keys[i] = __longlong_as_double(0x7FEFFFFFFFFFFFFFLL);
#pragma unroll 2
  for (int mi = 0; mi < CHL; ++mi) {
    const float4 c = pts[mi];
    float dot = __fadd_rn(__fadd_rn(__fmul_rn(q.x, c.x), __fmul_rn(q.y, c.y)),
                          __fmul_rn(q.z, c.z));
    float d = __fsub_rn(__fadd_rn(q.w, c.w), __fmul_rn(2.0f, dot));
    d = fmaxf(d, 0.0f);
    u64 kb_ = ((u64)__float_as_uint(d) << 32) | (u32)(m0 + mi);
    double kd = __longlong_as_double((long long)kb_);
    if (kd < keys[KK - 1]) {
#pragma unroll
      for (int i = 0; i < KK; ++i) {
        double lo = fmin(keys[i], kd);
        kd = fmax(keys[i], kd);
        keys[i] = lo;
      }
    }
  }
  const int t = b * NN + n;
#pragma unroll
  for (int j = 0; j < KK; ++j)
    cand[(size_t)(ch * KK + j) * (BB * NN) + t] = (u64)__double_as_longlong(keys[j]);
}

// ---------------- KNN pass 2 (unchanged) ----------------
__global__ __launch_bounds__(256) void k_knn2(const u64* __restrict__ cand,
                                              int* __restrict__ idx) {
  int t = blockIdx.x * 256 + threadIdx.x;
  if (t >= BB * NN) return;
  double best[KK];
#pragma unroll
  for (int i = 0; i < KK; ++i) best[i] = __longlong_as_double(0x7FEFFFFFFFFFFFFFLL);
  for (int i = 0; i < CHN * KK; ++i) {
    double kd = __longlong_as_double((long long)cand[(size_t)i * (BB * NN) + t]);
    if (kd < best[KK - 1]) {
#pragma unroll
      for (int q = 0; q < KK; ++q) {
        double lo = fmin(best[q], kd);
        kd = fmax(best[q], kd);
        best[q] = lo;
      }
    }
  }
#pragma unroll
  for (int j = 0; j < KK; ++j)
    idx[t * KK + j] = (int)((u64)__double_as_longlong(best[j]) & 0xffffffffu);
}

// ---------------- split-bf16 helpers ----------------
__device__ __forceinline__ void splitf(float a, ushort_t& h, ushort_t& l) {
  u32 ab = __float_as_uint(a);
  h = (ushort_t)(ab >> 16);
  float hif = __uint_as_float(ab & 0xffff0000u);
  l = (ushort_t)(__float_as_uint(a - hif) >> 16);
}

// stage fp32 [128][128] matrix -> hi/lo bf16 planes in LDS, XOR-swizzled 16B slots
__device__ __forceinline__ void stage_mat(const float* __restrict__ G,
                                          ushort_t* Bh, ushort_t* Bl, int tid) {
  const float4* G4 = (const float4*)G;
#pragma unroll
  for (int i = 0; i < 16; ++i) {
    int f = i * 256 + tid;  // 0..4095 float4s
    int r = f >> 5, k4 = f & 31;
    float4 v = G4[f];
    ushort_t h0, l0, h1, l1, h2, l2, h3, l3;
    splitf(v.x, h0, l0);
    splitf(v.y, h1, l1);
    splitf(v.z, h2, l2);
    splitf(v.w, h3, l3);
    int slot = k4 >> 1;
    int sub = (k4 & 1) * 4;
    int base = r * 128 + ((slot ^ (r & 15)) * 8) + sub;
    uint2 ph = make_uint2((u32)h0 | ((u32)h1 << 16), (u32)h2 | ((u32)h3 << 16));
    uint2 pl = make_uint2((u32)l0 | ((u32)l1 << 16), (u32)l2 | ((u32)l3 << 16));
    *(uint2*)&Bh[base] = ph;
    *(uint2*)&Bl[base] = pl;
  }
}

// 128x128x128 split-bf16 GEMM core: acc[rt][ct] += A @ W^T (3-term split)
__device__ __forceinline__ void gemm128(const ushort_t* ABh, const ushort_t* ABl,
                                        const ushort_t* WBh, const ushort_t* WBl,
                                        f32x4 acc[4][4], int tid) {
  const int l = tid & 63, wid = tid >> 6;
  const int wrow = wid >> 1, wcol = wid & 1;
  const int lq = l >> 4, lr = l & 15;
#pragma unroll
  for (int ks = 0; ks < 4; ++ks) {
    const int sw8 = (((ks * 4 + lq) ^ lr) * 8);
    short8v ah[4], al[4], wh[4], wl[4];
#pragma unroll
    for (int rt = 0; rt < 4; ++rt) {
      int row = wrow * 64 + rt * 16 + lr;
      ah[rt] = *(const short8v*)&ABh[row * 128 + sw8];
      al[rt] = *(const short8v*)&ABl[row * 128 + sw8];
    }
#pragma unroll
    for (int ct = 0; ct < 4; ++ct) {
      int cc = wcol * 64 + ct * 16 + lr;
      wh[ct] = *(const short8v*)&WBh[cc * 128 + sw8];
      wl[ct] = *(const short8v*)&WBl[cc * 128 + sw8];
    }
#pragma unroll
    for (int rt = 0; rt < 4; ++rt)
#pragma unroll
      for (int ct = 0; ct < 4; ++ct) {
        acc[rt][ct] = __builtin_amdgcn_mfma_f32_16x16x32_bf16(ah[rt], wh[ct], acc[rt][ct], 0, 0, 0);
        acc[rt][ct] = __builtin_amdgcn_mfma_f32_16x16x32_bf16(ah[rt], wl[ct], acc[rt][ct], 0, 0, 0);
        acc[rt][ct] = __builtin_amdgcn_mfma_f32_16x16x32_bf16(al[rt], wh[ct], acc[rt][ct], 0, 0, 0);
      }
  }
}

// ---------------- plain GEMM: C[M,128] = A @ W^T (up to 3 weights share A) ------
template <int NW>
__global__ __launch_bounds__(256, 1) void k_mm(const float* __restrict__ A,
                                               const float* __restrict__ Wa,
                                               const float* __restrict__ Wb,
                                               const float* __restrict__ Wc,
                                               float* __restrict__ Ca,
                                               float* __restrict__ Cb,
                                               float* __restrict__ Cc) {
  __shared__ ushort_t ABh[128 * 128], ABl[128 * 128], WBh[128 * 128], WBl[128 * 128];
  const int tid = threadIdx.x;
  const int Rbase = blockIdx.x * 128;
  stage_mat(A + (size_t)Rbase * 128, ABh, ABl, tid);
  const int l = tid & 63, wid = tid >> 6;
  const int wrow = wid >> 1, wcol = wid & 1;
  const int lq = l >> 4, lr = l & 15;
  const float* Ws[3] = {Wa, Wb, Wc};
  float* Cs[3] = {Ca, Cb, Cc};
#pragma unroll
  for (int w = 0; w < NW; ++w) {
    if (w) __syncthreads();  // prior gemm reads done before Wbuf overwrite
    stage_mat(Ws[w], WBh, WBl, tid);
    __syncthreads();
    f32x4 acc[4][4];
#pragma unroll
    for (int rt = 0; rt < 4; ++rt)
#pragma unroll
      for (int ct = 0; ct < 4; ++ct) acc[rt][ct] = (f32x4)0.f;
    gemm128(ABh, ABl, WBh, WBl, acc, tid);
#pragma unroll
    for (int rt = 0; rt < 4; ++rt)
#pragma unroll
      for (int ct = 0; ct < 4; ++ct) {
        int c = wcol * 64 + ct * 16 + lr;
#pragma unroll
        for (int reg = 0; reg < 4; ++reg) {
          int R = Rbase + wrow * 64 + rt * 16 + lq * 4 + reg;
          Cs[w][(size_t)R * 128 + c] = acc[rt][ct][reg];
        }
      }
  }
}

// ---------------- fused chain: h1 -> pos -> u -> z -> logits -> softmax -> out ----
__global__ __launch_bounds__(256, 1) void k_fused(
    const float4* __restrict__ xyzw, const int* __restrict__ idx,
    const float* __restrict__ qb, const float* __restrict__ kb,
    const float* __restrict__ vb, const float* __restrict__ pW1,
    const float* __restrict__ pb1, const float* __restrict__ pg,
    const float* __restrict__ pbeta, const float* __restrict__ pm,
    const float* __restrict__ pv, const float* __restrict__ pW2,
    const float* __restrict__ pb2, const float* __restrict__ aW1,
    const float* __restrict__ ab1, const float* __restrict__ ag,
    const float* __restrict__ abeta, const float* __restrict__ am,
    const float* __restrict__ av, const float* __restrict__ aW2,
    const float* __restrict__ ab2, float* __restrict__ outb) {
  __shared__ ushort_t ABh[128 * 128], ABl[128 * 128], WBh[128 * 128], WBl[128 * 128];
  __shared__ float4 fW1[128];
  __shared__ float sA[128], tA[128], pB2[128], aB2[128];
  __shared__ int idxs[128];
  const int tid = threadIdx.x;
  const int Qbase = blockIdx.x * 8;
  const int b = Qbase >> 13;

  if (tid < 128) {
    int c = tid;
    idxs[c] = idx[Qbase * KK + c];
    float s1 = pg[c] / sqrtf(pv[c] + EPSV);
    fW1[c] = make_float4(pW1[c * 3] * s1, pW1[c * 3 + 1] * s1, pW1[c * 3 + 2] * s1,
                         (pb1[c] - pm[c]) * s1 + pbeta[c]);
    float s2 = ag[c] / sqrtf(av[c] + EPSV);
    sA[c] = s2;
    tA[c] = (ab1[c] - am[c]) * s2 + abeta[c];
    pB2[c] = pb2[c];
    aB2[c] = ab2[c];
  }
  stage_mat(pW2, WBh, WBl, tid);
  __syncthreads();

  // h1 tile -> A planes
  {
    int r = tid >> 1, chalf = tid & 1;
    int Q = Qbase + (r >> 4);
    int m = idxs[(r >> 4) * 16 + (r & 15)];
    float4 pq = xyzw[Q];
    float4 pn = xyzw[b * NN + m];
    float rx = pn.x - pq.x, ry = pn.y - pq.y, rz = pn.z - pq.z;
#pragma unroll
    for (int g = 0; g < 8; ++g) {
      short8v vh, vl;
      int c0 = chalf * 64 + g * 8;
#pragma unroll
      for (int e = 0; e < 8; ++e) {
        float4 w = fW1[c0 + e];
        float h = fmaxf(fmaf(rz, w.z, fmaf(ry, w.y, fmaf(rx, w.x, w.w))), 0.f);
        ushort_t hh, ll;
        splitf(h, hh, ll);
        vh[e] = (short)hh;
        vl[e] = (short)ll;
      }
      int sw = (chalf * 8 + g) ^ (r & 15);
      *(short8v*)&ABh[r * 128 + sw * 8] = vh;
      *(short8v*)&ABl[r * 128 + sw * 8] = vl;
    }
  }
  __syncthreads();

  const int l = tid & 63, wid = tid >> 6;
  const int wrow = wid >> 1, wcol = wid & 1;
  const int lq = l >> 4, lr = l & 15;

  // GEMM0: pos = h1 @ pW2^T + pb2  (kept in accumulators)
  f32x4 pos_[4][4];
#pragma unroll
  for (int rt = 0; rt < 4; ++rt)
#pragma unroll
    for (int ct = 0; ct < 4; ++ct) pos_[rt][ct] = (f32x4)0.f;
  gemm128(ABh, ABl, WBh, WBl, pos_, tid);
#pragma unroll
  for (int ct = 0; ct < 4; ++ct) {
    float pb2v = pB2[wcol * 64 + ct * 16 + lr];
#pragma unroll
    for (int rt = 0; rt < 4; ++rt)
#pragma unroll
      for (int reg = 0; reg < 4; ++reg) pos_[rt][ct][reg] += pb2v;
  }
  __syncthreads();

  // u = q - k_gather + pos -> A planes ; stage aW1
#pragma unroll
  for (int rt = 0; rt < 4; ++rt) {
    int qi_loc = wrow * 4 + rt;
    int Q = Qbase + qi_loc;
    int mr[4];
#pragma unroll
    for (int reg = 0; reg < 4; ++reg) mr[reg] = b * NN + idxs[qi_loc * 16 + lq * 4 + reg];
#pragma unroll
    for (int ct = 0; ct < 4; ++ct) {
      int c = wcol * 64 + ct * 16 + lr;
      float qv = qb[(size_t)Q * 128 + c];
#pragma unroll
      for (int reg = 0; reg < 4; ++reg) {
        float u = qv - kb[(size_t)mr[reg] * 128 + c] + pos_[rt][ct][reg];
        ushort_t hh, ll;
        splitf(u, hh, ll);
        int R15 = lq * 4 + reg;
        int row = wrow * 64 + rt * 16 + R15;
        int base = row * 128 + (((c >> 3) ^ R15) * 8) + (c & 7);
        ABh[base] = hh;
        ABl[base] = ll;
      }
    }
  }
  stage_mat(aW1, WBh, WBl, tid);
  __syncthreads();

  // GEMM1: z = relu(BN(u @ aW1^T + ab1)) (folded)
  f32x4 acc[4][4];
#pragma unroll
  for (int rt = 0; rt < 4; ++rt)
#pragma unroll
    for (int ct = 0; ct < 4; ++ct) acc[rt][ct] = (f32x4)0.f;
  gemm128(ABh, ABl, WBh, WBl, acc, tid);
  __syncthreads();
#pragma unroll
  for (int ct = 0; ct < 4; ++ct) {
    int c = wcol * 64 + ct * 16 + lr;
    float sc = sA[c], tc = tA[c];
#pragma unroll
    for (int rt = 0; rt < 4; ++rt) {
#pragma unroll
      for (int reg = 0; reg < 4; ++reg) {
        float z = fmaxf(fmaf(acc[rt][ct][reg], sc, tc), 0.f);
        ushort_t hh, ll;
        splitf(z, hh, ll);
        int R15 = lq * 4 + reg;
        int row = wrow * 64 + rt * 16 + R15;
        int base = row * 128 + (((c >> 3) ^ R15) * 8) + (c & 7);
        ABh[base] = hh;
        ABl[base] = ll;
      }
    }
  }
  stage_mat(aW2, WBh, WBl, tid);
  __syncthreads();

  // GEMM2: logits = z @ aW2^T + ab2 ; softmax over the 16 rows of each query; combine
#pragma unroll
  for (int rt = 0; rt < 4; ++rt)
#pragma unroll
    for (int ct = 0; ct < 4; ++ct) acc[rt][ct] = (f32x4)0.f;
  gemm128(ABh, ABl, WBh, WBl, acc, tid);

#pragma unroll
  for (int rt = 0; rt < 4; ++rt) {
    int qi_loc = wrow * 4 + rt;
    int Q = Qbase + qi_loc;
    int mr[4];
#pragma unroll
    for (int reg = 0; reg < 4; ++reg) mr[reg] = b * NN + idxs[qi_loc * 16 + lq * 4 + reg];
#pragma unroll
    for (int ct = 0; ct < 4; ++ct) {
      int c = wcol * 64 + ct * 16 + lr;
      float ab2v = aB2[c];
      float lg[4];
#pragma unroll
      for (int reg = 0; reg < 4; ++reg) lg[reg] = acc[rt][ct][reg] + ab2v;
      float mx = fmaxf(fmaxf(lg[0], lg[1]), fmaxf(lg[2], lg[3]));
      mx = fmaxf(mx, __shfl_xor(mx, 16));
      mx = fmaxf(mx, __shfl_xor(mx, 32));
      float s = 0.f, o = 0.f;
#pragma unroll
      for (int reg = 0; reg < 4; ++reg) {
        float e_ = expf(lg[reg] - mx);
        s += e_;
        float vv = vb[(size_t)mr[reg] * 128 + c] + pos_[rt][ct][reg];
        o = fmaf(e_, vv, o);
      }
      s += __shfl_xor(s, 16);
      s += __shfl_xor(s, 32);
      o += __shfl_xor(o, 16);
      o += __shfl_xor(o, 32);
      if (lq == 0) outb[(size_t)Q * 128 + c] = o / s;
    }
  }
}

// ---------------- host launch ----------------
extern "C" void kernel_launch(void* const* d_in, const int* in_sizes, int n_in,
                              void* d_out, int out_size, void* d_ws, size_t ws_size,
                              hipStream_t stream) {
  const float* xyz = (const float*)d_in[0];
  const float* feat = (const float*)d_in[1];
  const float* Wq = (const float*)d_in[2];
  const float* Wk = (const float*)d_in[3];
  const float* Wv = (const float*)d_in[4];
  const float* pW1 = (const float*)d_in[5];
  const float* pb1 = (const float*)d_in[6];
  const float* pg = (const float*)d_in[7];
  const float* pbeta = (const float*)d_in[8];
  const float* pmean = (const float*)d_in[9];
  const float* pvar = (const float*)d_in[10];
  const float* pW2 = (const float*)d_in[11];
  const float* pb2 = (const float*)d_in[12];
  const float* aW1 = (const float*)d_in[13];
  const float* ab1 = (const float*)d_in[14];
  const float* ag = (const float*)d_in[15];
  const float* abeta = (const float*)d_in[16];
  const float* amean = (const float*)d_in[17];
  const float* avar = (const float*)d_in[18];
  const float* aW2 = (const float*)d_in[19];
  const float* ab2 = (const float*)d_in[20];
  const float* Wout = (const float*)d_in[21];
  float* out = (float*)d_out;
  char* ws = (char*)d_ws;

  size_t off = 0;
  auto alloc = [&](size_t bytes) {
    size_t r = off;
    off += (bytes + 255) & ~(size_t)255;
    return r;
  };
  float4* xyzw = (float4*)(ws + alloc((size_t)BB * NN * 16));
  int* idx = (int*)(ws + alloc((size_t)BB * NN * KK * 4));
  size_t o_qb = alloc((size_t)BB * NN * CC * 4);
  size_t o_kb = alloc((size_t)BB * NN * CC * 4);
  size_t o_vb = alloc((size_t)BB * NN * CC * 4);
  size_t o_ob = alloc((size_t)BB * NN * CC * 4);
  float* qb = (float*)(ws + o_qb);
  float* kb = (float*)(ws + o_kb);
  float* vb = (float*)(ws + o_vb);
  float* outb = (float*)(ws + o_ob);
  // KNN candidate buffer (32 MB) aliases qb..outb (dead until after k_knn2).
  u64* cand = (u64*)(ws + o_qb);

  k_prep<<<(BB * NN) / 256, 256, 0, stream>>>(xyz, xyzw);
  k_knn1<<<dim3((BB * NN) / 256, CHN), 256, 0, stream>>>(xyzw, cand);
  k_knn2<<<(BB * NN) / 256, 256, 0, stream>>>(cand, idx);

  k_mm<3><<<(BB * NN) / 128, 256, 0, stream>>>(feat, Wq, Wk, Wv, qb, kb, vb);

  k_fused<<<(BB * NN * KK) / 128, 256, 0, stream>>>(
      xyzw, idx, qb, kb, vb, pW1, pb1, pg, pbeta, pmean, pvar, pW2, pb2, aW1, ab1,
      ag, abeta, amean, avar, aW2, ab2, outb);

  k_mm<1><<<(BB * NN) / 128, 256, 0, stream>>>(outb, Wout, nullptr, nullptr, out,
                                               nullptr, nullptr);
}

// Round 4
// 495.650 us; speedup vs baseline: 2.6732x; 1.0697x over previous
//
#include <hip/hip_runtime.h>
#include <cstdint>
#include <cstddef>

#define BB 2
#define NN 8192
#define CC 128
#define KK 16
#define CHN 16
#define CHL (NN / CHN)
#define EPSV 1e-5f
#define CAP 20

typedef unsigned long long u64;
typedef unsigned int u32;
typedef unsigned short ushort_t;
typedef short short8v __attribute__((ext_vector_type(8)));
typedef float f32x4 __attribute__((ext_vector_type(4)));

#if __has_builtin(__builtin_amdgcn_fmed3f)
#define MED3(x, y, z) __builtin_amdgcn_fmed3f((x), (y), (z))
#else
#define MED3(x, y, z) fminf(fmaxf((x), (y)), fmaxf(fminf((x), (y)), (z)))
#endif

// ---------------- prep: pack (x,y,z, sq) ----------------
__global__ __launch_bounds__(256) void k_prep(const float* __restrict__ xyz,
                                              float4* __restrict__ xyzw) {
  int t = blockIdx.x * 256 + threadIdx.x;
  if (t >= BB * NN) return;
  float x = xyz[t * 3 + 0], y = xyz[t * 3 + 1], z = xyz[t * 3 + 2];
  float sq = __fadd_rn(__fadd_rn(__fmul_rn(x, x), __fmul_rn(y, y)), __fmul_rn(z, z));
  xyzw[t] = make_float4(x, y, z, sq);
}

__device__ __forceinline__ float distf(const float4& q, const float4& c) {
  float dot = __fadd_rn(__fadd_rn(__fmul_rn(q.x, c.x), __fmul_rn(q.y, c.y)),
                        __fmul_rn(q.z, c.z));
  float d = __fsub_rn(__fadd_rn(q.w, c.w), __fmul_rn(2.0f, dot));
  return fmaxf(d, 0.0f);
}

// ---------------- KNN pass 1: two-phase (med3 value scan + index recovery) ------
__global__ __launch_bounds__(256) void k_knn1(const float4* __restrict__ xyzw,
                                              u32* __restrict__ cand_d,
                                              u32* __restrict__ cand_i) {
  __shared__ float4 pts[CHL];
  __shared__ u64 buf[4][64 * CAP];
  const int tid = threadIdx.x;
  const int bx = blockIdx.x;
  const int ch = blockIdx.y;
  const int b = bx / (NN / 256);
  const int n = (bx % (NN / 256)) * 256 + tid;
  const int m0 = ch * CHL;
  for (int i = tid; i < CHL; i += 256) pts[i] = xyzw[b * NN + m0 + i];
  const float4 q = xyzw[b * NN + n];
  __syncthreads();

  // phase 1: smallest-16 VALUES via branchless med3 insertion (multiset-exact)
  float a[KK];
#pragma unroll
  for (int i = 0; i < KK; ++i) a[i] = 3.4e38f;
#pragma unroll 2
  for (int mi = 0; mi < CHL; ++mi) {
    const float d = distf(q, pts[mi]);
#pragma unroll
    for (int i = KK - 1; i >= 1; --i) a[i] = MED3(d, a[i - 1], a[i]);
    a[0] = fminf(d, a[0]);
  }
  const float thr = a[KK - 1];  // exact 16th-smallest distance in chunk

  // phase 2: collect all (d,m) with d <= thr (>=16, usually ==16)
  u64* mybuf = &buf[tid >> 6][(tid & 63) * CAP];
  int cnt = 0;
  for (int mi = 0; mi < CHL; ++mi) {
    const float d = distf(q, pts[mi]);
    if (d <= thr) {
      if (cnt < CAP) mybuf[cnt] = ((u64)__float_as_uint(d) << 32) | (u32)(m0 + mi);
      ++cnt;
    }
  }

  // merge: exact (dist, idx) lexicographic top-16 (f64-bit-order trick)
  double keys[KK];
#pragma unroll
  for (int i = 0; i < KK; ++i) keys[i] = __longlong_as_double(0x7FEFFFFFFFFFFFFFLL);
  if (cnt <= CAP) {
    for (int j = 0; j < cnt; ++j) {
      double kd = __longlong_as_double((long long)mybuf[j]);
      if (kd < keys[KK - 1]) {
#pragma unroll
        for (int i = 0; i < KK; ++i) {
          double lo = fmin(keys[i], kd);
          kd = fmax(keys[i], kd);
          keys[i] = lo;
        }
      }
    }
  } else {
    // pathological tie overflow: exact full rescan (never for random data)
    for (int mi = 0; mi < CHL; ++mi) {
      const float d = distf(q, pts[mi]);
      u64 kb_ = ((u64)__float_as_uint(d) << 32) | (u32)(m0 + mi);
      double kd = __longlong_as_double((long long)kb_);
      if (kd < keys[KK - 1]) {
#pragma unroll
        for (int i = 0; i < KK; ++i) {
          double lo = fmin(keys[i], kd);
          kd = fmax(keys[i], kd);
          keys[i] = lo;
        }
      }
    }
  }
  const int t = b * NN + n;
#pragma unroll
  for (int j = 0; j < KK; ++j) {
    u64 kk = (u64)__double_as_longlong(keys[j]);
    cand_d[(size_t)(ch * KK + j) * (BB * NN) + t] = (u32)(kk >> 32);
    cand_i[(size_t)(ch * KK + j) * (BB * NN) + t] = (u32)kk;
  }
}

// ---------------- KNN pass 2: two-phase merge of CHN chunk top-16s ----------------
__global__ __launch_bounds__(128) void k_knn2(const u32* __restrict__ cand_d,
                                              const u32* __restrict__ cand_i,
                                              int* __restrict__ idx) {
  const int t = blockIdx.x * 128 + threadIdx.x;
  float a[KK];
#pragma unroll
  for (int i = 0; i < KK; ++i) a[i] = 3.4e38f;
#pragma unroll 4
  for (int i = 0; i < CHN * KK; ++i) {
    float d = __uint_as_float(cand_d[(size_t)i * (BB * NN) + t]);
#pragma unroll
    for (int s = KK - 1; s >= 1; --s) a[s] = MED3(d, a[s - 1], a[s]);
    a[0] = fminf(d, a[0]);
  }
  const float thr = a[KK - 1];
  double keys[KK];
#pragma unroll
  for (int i = 0; i < KK; ++i) keys[i] = __longlong_as_double(0x7FEFFFFFFFFFFFFFLL);
  for (int i = 0; i < CHN * KK; ++i) {
    u32 db = cand_d[(size_t)i * (BB * NN) + t];
    float d = __uint_as_float(db);
    if (d <= thr) {
      u64 kb_ = ((u64)db << 32) | (u64)cand_i[(size_t)i * (BB * NN) + t];
      double kd = __longlong_as_double((long long)kb_);
      if (kd < keys[KK - 1]) {
#pragma unroll
        for (int s = 0; s < KK; ++s) {
          double lo = fmin(keys[s], kd);
          kd = fmax(keys[s], kd);
          keys[s] = lo;
        }
      }
    }
  }
#pragma unroll
  for (int j = 0; j < KK; ++j)
    idx[t * KK + j] = (int)((u64)__double_as_longlong(keys[j]) & 0xffffffffu);
}

// ---------------- split-bf16 helpers ----------------
__device__ __forceinline__ void splitf(float a, ushort_t& h, ushort_t& l) {
  u32 ab = __float_as_uint(a);
  h = (ushort_t)(ab >> 16);
  float hif = __uint_as_float(ab & 0xffff0000u);
  l = (ushort_t)(__float_as_uint(a - hif) >> 16);
}

// stage fp32 [128][128] matrix -> hi/lo bf16 planes in LDS, XOR-swizzled 16B slots
__device__ __forceinline__ void stage_mat(const float* __restrict__ G,
                                          ushort_t* Bh, ushort_t* Bl, int tid) {
  const float4* G4 = (const float4*)G;
#pragma unroll
  for (int i = 0; i < 16; ++i) {
    int f = i * 256 + tid;  // 0..4095 float4s
    int r = f >> 5, k4 = f & 31;
    float4 v = G4[f];
    ushort_t h0, l0, h1, l1, h2, l2, h3, l3;
    splitf(v.x, h0, l0);
    splitf(v.y, h1, l1);
    splitf(v.z, h2, l2);
    splitf(v.w, h3, l3);
    int slot = k4 >> 1;
    int sub = (k4 & 1) * 4;
    int base = r * 128 + ((slot ^ (r & 15)) * 8) + sub;
    uint2 ph = make_uint2((u32)h0 | ((u32)h1 << 16), (u32)h2 | ((u32)h3 << 16));
    uint2 pl = make_uint2((u32)l0 | ((u32)l1 << 16), (u32)l2 | ((u32)l3 << 16));
    *(uint2*)&Bh[base] = ph;
    *(uint2*)&Bl[base] = pl;
  }
}

// 128x128x128 split-bf16 GEMM core: acc[rt][ct] += A @ W^T (3-term split)
__device__ __forceinline__ void gemm128(const ushort_t* ABh, const ushort_t* ABl,
                                        const ushort_t* WBh, const ushort_t* WBl,
                                        f32x4 acc[4][4], int tid) {
  const int l = tid & 63, wid = tid >> 6;
  const int wrow = wid >> 1, wcol = wid & 1;
  const int lq = l >> 4, lr = l & 15;
#pragma unroll
  for (int ks = 0; ks < 4; ++ks) {
    const int sw8 = (((ks * 4 + lq) ^ lr) * 8);
    short8v ah[4], al[4], wh[4], wl[4];
#pragma unroll
    for (int rt = 0; rt < 4; ++rt) {
      int row = wrow * 64 + rt * 16 + lr;
      ah[rt] = *(const short8v*)&ABh[row * 128 + sw8];
      al[rt] = *(const short8v*)&ABl[row * 128 + sw8];
    }
#pragma unroll
    for (int ct = 0; ct < 4; ++ct) {
      int cc = wcol * 64 + ct * 16 + lr;
      wh[ct] = *(const short8v*)&WBh[cc * 128 + sw8];
      wl[ct] = *(const short8v*)&WBl[cc * 128 + sw8];
    }
#pragma unroll
    for (int rt = 0; rt < 4; ++rt)
#pragma unroll
      for (int ct = 0; ct < 4; ++ct) {
        acc[rt][ct] = __builtin_amdgcn_mfma_f32_16x16x32_bf16(ah[rt], wh[ct], acc[rt][ct], 0, 0, 0);
        acc[rt][ct] = __builtin_amdgcn_mfma_f32_16x16x32_bf16(ah[rt], wl[ct], acc[rt][ct], 0, 0, 0);
        acc[rt][ct] = __builtin_amdgcn_mfma_f32_16x16x32_bf16(al[rt], wh[ct], acc[rt][ct], 0, 0, 0);
      }
  }
}

// ---------------- plain GEMM: C[M,128] = A @ W^T (up to 3 weights share A) ------
template <int NW>
__global__ __launch_bounds__(256, 1) void k_mm(const float* __restrict__ A,
                                               const float* __restrict__ Wa,
                                               const float* __restrict__ Wb,
                                               const float* __restrict__ Wc,
                                               float* __restrict__ Ca,
                                               float* __restrict__ Cb,
                                               float* __restrict__ Cc) {
  __shared__ ushort_t ABh[128 * 128], ABl[128 * 128], WBh[128 * 128], WBl[128 * 128];
  const int tid = threadIdx.x;
  const int Rbase = blockIdx.x * 128;
  stage_mat(A + (size_t)Rbase * 128, ABh, ABl, tid);
  const int l = tid & 63, wid = tid >> 6;
  const int wrow = wid >> 1, wcol = wid & 1;
  const int lq = l >> 4, lr = l & 15;
  const float* Ws[3] = {Wa, Wb, Wc};
  float* Cs[3] = {Ca, Cb, Cc};
#pragma unroll
  for (int w = 0; w < NW; ++w) {
    if (w) __syncthreads();  // prior gemm reads done before Wbuf overwrite
    stage_mat(Ws[w], WBh, WBl, tid);
    __syncthreads();
    f32x4 acc[4][4];
#pragma unroll
    for (int rt = 0; rt < 4; ++rt)
#pragma unroll
      for (int ct = 0; ct < 4; ++ct) acc[rt][ct] = (f32x4)0.f;
    gemm128(ABh, ABl, WBh, WBl, acc, tid);
#pragma unroll
    for (int rt = 0; rt < 4; ++rt)
#pragma unroll
      for (int ct = 0; ct < 4; ++ct) {
        int c = wcol * 64 + ct * 16 + lr;
#pragma unroll
        for (int reg = 0; reg < 4; ++reg) {
          int R = Rbase + wrow * 64 + rt * 16 + lq * 4 + reg;
          Cs[w][(size_t)R * 128 + c] = acc[rt][ct][reg];
        }
      }
  }
}

// ---------------- fused chain: h1 -> pos -> u -> z -> logits -> softmax -> out ----
__global__ __launch_bounds__(256, 1) void k_fused(
    const float4* __restrict__ xyzw, const int* __restrict__ idx,
    const float* __restrict__ qb, const float* __restrict__ kb,
    const float* __restrict__ vb, const float* __restrict__ pW1,
    const float* __restrict__ pb1, const float* __restrict__ pg,
    const float* __restrict__ pbeta, const float* __restrict__ pm,
    const float* __restrict__ pv, const float* __restrict__ pW2,
    const float* __restrict__ pb2, const float* __restrict__ aW1,
    const float* __restrict__ ab1, const float* __restrict__ ag,
    const float* __restrict__ abeta, const float* __restrict__ am,
    const float* __restrict__ av, const float* __restrict__ aW2,
    const float* __restrict__ ab2, float* __restrict__ outb) {
  __shared__ ushort_t ABh[128 * 128], ABl[128 * 128], WBh[128 * 128], WBl[128 * 128];
  __shared__ float4 fW1[128];
  __shared__ float sA[128], tA[128], pB2[128], aB2[128];
  __shared__ int idxs[128];
  const int tid = threadIdx.x;
  const int Qbase = blockIdx.x * 8;
  const int b = Qbase >> 13;

  if (tid < 128) {
    int c = tid;
    idxs[c] = idx[Qbase * KK + c];
    float s1 = pg[c] / sqrtf(pv[c] + EPSV);
    fW1[c] = make_float4(pW1[c * 3] * s1, pW1[c * 3 + 1] * s1, pW1[c * 3 + 2] * s1,
                         (pb1[c] - pm[c]) * s1 + pbeta[c]);
    float s2 = ag[c] / sqrtf(av[c] + EPSV);
    sA[c] = s2;
    tA[c] = (ab1[c] - am[c]) * s2 + abeta[c];
    pB2[c] = pb2[c];
    aB2[c] = ab2[c];
  }
  stage_mat(pW2, WBh, WBl, tid);
  __syncthreads();

  // h1 tile -> A planes
  {
    int r = tid >> 1, chalf = tid & 1;
    int Q = Qbase + (r >> 4);
    int m = idxs[(r >> 4) * 16 + (r & 15)];
    float4 pq = xyzw[Q];
    float4 pn = xyzw[b * NN + m];
    float rx = pn.x - pq.x, ry = pn.y - pq.y, rz = pn.z - pq.z;
#pragma unroll
    for (int g = 0; g < 8; ++g) {
      short8v vh, vl;
      int c0 = chalf * 64 + g * 8;
#pragma unroll
      for (int e = 0; e < 8; ++e) {
        float4 w = fW1[c0 + e];
        float h = fmaxf(fmaf(rz, w.z, fmaf(ry, w.y, fmaf(rx, w.x, w.w))), 0.f);
        ushort_t hh, ll;
        splitf(h, hh, ll);
        vh[e] = (short)hh;
        vl[e] = (short)ll;
      }
      int sw = (chalf * 8 + g) ^ (r & 15);
      *(short8v*)&ABh[r * 128 + sw * 8] = vh;
      *(short8v*)&ABl[r * 128 + sw * 8] = vl;
    }
  }
  __syncthreads();

  const int l = tid & 63, wid = tid >> 6;
  const int wrow = wid >> 1, wcol = wid & 1;
  const int lq = l >> 4, lr = l & 15;

  // GEMM0: pos = h1 @ pW2^T + pb2  (kept in accumulators)
  f32x4 pos_[4][4];
#pragma unroll
  for (int rt = 0; rt < 4; ++rt)
#pragma unroll
    for (int ct = 0; ct < 4; ++ct) pos_[rt][ct] = (f32x4)0.f;
  gemm128(ABh, ABl, WBh, WBl, pos_, tid);
#pragma unroll
  for (int ct = 0; ct < 4; ++ct) {
    float pb2v = pB2[wcol * 64 + ct * 16 + lr];
#pragma unroll
    for (int rt = 0; rt < 4; ++rt)
#pragma unroll
      for (int reg = 0; reg < 4; ++reg) pos_[rt][ct][reg] += pb2v;
  }
  __syncthreads();

  // u = q - k_gather + pos -> A planes ; stage aW1
#pragma unroll
  for (int rt = 0; rt < 4; ++rt) {
    int qi_loc = wrow * 4 + rt;
    int Q = Qbase + qi_loc;
    int mr[4];
#pragma unroll
    for (int reg = 0; reg < 4; ++reg) mr[reg] = b * NN + idxs[qi_loc * 16 + lq * 4 + reg];
#pragma unroll
    for (int ct = 0; ct < 4; ++ct) {
      int c = wcol * 64 + ct * 16 + lr;
      float qv = qb[(size_t)Q * 128 + c];
#pragma unroll
      for (int reg = 0; reg < 4; ++reg) {
        float u = qv - kb[(size_t)mr[reg] * 128 + c] + pos_[rt][ct][reg];
        ushort_t hh, ll;
        splitf(u, hh, ll);
        int R15 = lq * 4 + reg;
        int row = wrow * 64 + rt * 16 + R15;
        int base = row * 128 + (((c >> 3) ^ R15) * 8) + (c & 7);
        ABh[base] = hh;
        ABl[base] = ll;
      }
    }
  }
  stage_mat(aW1, WBh, WBl, tid);
  __syncthreads();

  // GEMM1: z = relu(BN(u @ aW1^T + ab1)) (folded)
  f32x4 acc[4][4];
#pragma unroll
  for (int rt = 0; rt < 4; ++rt)
#pragma unroll
    for (int ct = 0; ct < 4; ++ct) acc[rt][ct] = (f32x4)0.f;
  gemm128(ABh, ABl, WBh, WBl, acc, tid);
  __syncthreads();
#pragma unroll
  for (int ct = 0; ct < 4; ++ct) {
    int c = wcol * 64 + ct * 16 + lr;
    float sc = sA[c], tc = tA[c];
#pragma unroll
    for (int rt = 0; rt < 4; ++rt) {
#pragma unroll
      for (int reg = 0; reg < 4; ++reg) {
        float z = fmaxf(fmaf(acc[rt][ct][reg], sc, tc), 0.f);
        ushort_t hh, ll;
        splitf(z, hh, ll);
        int R15 = lq * 4 + reg;
        int row = wrow * 64 + rt * 16 + R15;
        int base = row * 128 + (((c >> 3) ^ R15) * 8) + (c & 7);
        ABh[base] = hh;
        ABl[base] = ll;
      }
    }
  }
  stage_mat(aW2, WBh, WBl, tid);
  __syncthreads();

  // GEMM2: logits = z @ aW2^T + ab2 ; softmax over the 16 rows of each query; combine
#pragma unroll
  for (int rt = 0; rt < 4; ++rt)
#pragma unroll
    for (int ct = 0; ct < 4; ++ct) acc[rt][ct] = (f32x4)0.f;
  gemm128(ABh, ABl, WBh, WBl, acc, tid);

#pragma unroll
  for (int rt = 0; rt < 4; ++rt) {
    int qi_loc = wrow * 4 + rt;
    int Q = Qbase + qi_loc;
    int mr[4];
#pragma unroll
    for (int reg = 0; reg < 4; ++reg) mr[reg] = b * NN + idxs[qi_loc * 16 + lq * 4 + reg];
#pragma unroll
    for (int ct = 0; ct < 4; ++ct) {
      int c = wcol * 64 + ct * 16 + lr;
      float ab2v = aB2[c];
      float lg[4];
#pragma unroll
      for (int reg = 0; reg < 4; ++reg) lg[reg] = acc[rt][ct][reg] + ab2v;
      float mx = fmaxf(fmaxf(lg[0], lg[1]), fmaxf(lg[2], lg[3]));
      mx = fmaxf(mx, __shfl_xor(mx, 16));
      mx = fmaxf(mx, __shfl_xor(mx, 32));
      float s = 0.f, o = 0.f;
#pragma unroll
      for (int reg = 0; reg < 4; ++reg) {
        float e_ = expf(lg[reg] - mx);
        s += e_;
        float vv = vb[(size_t)mr[reg] * 128 + c] + pos_[rt][ct][reg];
        o = fmaf(e_, vv, o);
      }
      s += __shfl_xor(s, 16);
      s += __shfl_xor(s, 32);
      o += __shfl_xor(o, 16);
      o += __shfl_xor(o, 32);
      if (lq == 0) outb[(size_t)Q * 128 + c] = o / s;
    }
  }
}

// ---------------- host launch ----------------
extern "C" void kernel_launch(void* const* d_in, const int* in_sizes, int n_in,
                              void* d_out, int out_size, void* d_ws, size_t ws_size,
                              hipStream_t stream) {
  const float* xyz = (const float*)d_in[0];
  const float* feat = (const float*)d_in[1];
  const float* Wq = (const float*)d_in[2];
  const float* Wk = (const float*)d_in[3];
  const float* Wv = (const float*)d_in[4];
  const float* pW1 = (const float*)d_in[5];
  const float* pb1 = (const float*)d_in[6];
  const float* pg = (const float*)d_in[7];
  const float* pbeta = (const float*)d_in[8];
  const float* pmean = (const float*)d_in[9];
  const float* pvar = (const float*)d_in[10];
  const float* pW2 = (const float*)d_in[11];
  const float* pb2 = (const float*)d_in[12];
  const float* aW1 = (const float*)d_in[13];
  const float* ab1 = (const float*)d_in[14];
  const float* ag = (const float*)d_in[15];
  const float* abeta = (const float*)d_in[16];
  const float* amean = (const float*)d_in[17];
  const float* avar = (const float*)d_in[18];
  const float* aW2 = (const float*)d_in[19];
  const float* ab2 = (const float*)d_in[20];
  const float* Wout = (const float*)d_in[21];
  float* out = (float*)d_out;
  char* ws = (char*)d_ws;

  size_t off = 0;
  auto alloc = [&](size_t bytes) {
    size_t r = off;
    off += (bytes + 255) & ~(size_t)255;
    return r;
  };
  float4* xyzw = (float4*)(ws + alloc((size_t)BB * NN * 16));
  int* idx = (int*)(ws + alloc((size_t)BB * NN * KK * 4));
  size_t o_qb = alloc((size_t)BB * NN * CC * 4);
  size_t o_kb = alloc((size_t)BB * NN * CC * 4);
  size_t o_vb = alloc((size_t)BB * NN * CC * 4);
  size_t o_ob = alloc((size_t)BB * NN * CC * 4);
  float* qb = (float*)(ws + o_qb);
  float* kb = (float*)(ws + o_kb);
  float* vb = (float*)(ws + o_vb);
  float* outb = (float*)(ws + o_ob);
  // KNN candidate SoA planes (16 MB each) alias qb..outb (dead until after knn2).
  u32* cand_d = (u32*)(ws + o_qb);
  u32* cand_i = (u32*)(ws + o_vb);

  k_prep<<<(BB * NN) / 256, 256, 0, stream>>>(xyz, xyzw);
  k_knn1<<<dim3((BB * NN) / 256, CHN), 256, 0, stream>>>(xyzw, cand_d, cand_i);
  k_knn2<<<(BB * NN) / 128, 128, 0, stream>>>(cand_d, cand_i, idx);

  k_mm<3><<<(BB * NN) / 128, 256, 0, stream>>>(feat, Wq, Wk, Wv, qb, kb, vb);

  k_fused<<<(BB * NN * KK) / 128, 256, 0, stream>>>(
      xyzw, idx, qb, kb, vb, pW1, pb1, pg, pbeta, pmean, pvar, pW2, pb2, aW1, ab1,
      ag, abeta, amean, avar, aW2, ab2, outb);

  k_mm<1><<<(BB * NN) / 128, 256, 0, stream>>>(outb, Wout, nullptr, nullptr, out,
                                               nullptr, nullptr);
}

// Round 5
// 437.661 us; speedup vs baseline: 3.0274x; 1.1325x over previous
//
#include <hip/hip_runtime.h>
#include <cstdint>
#include <cstddef>

#define BB 2
#define NN 8192
#define CC 128
#define KK 16
#define CHN 16
#define CHL (NN / CHN)
#define EPSV 1e-5f
#define CAP 20

typedef unsigned long long u64;
typedef unsigned int u32;
typedef unsigned short ushort_t;
typedef short short8v __attribute__((ext_vector_type(8)));
typedef float f32x4 __attribute__((ext_vector_type(4)));

#if __has_builtin(__builtin_amdgcn_fmed3f)
#define MED3(x, y, z) __builtin_amdgcn_fmed3f((x), (y), (z))
#else
#define MED3(x, y, z) fminf(fmaxf((x), (y)), fmaxf(fminf((x), (y)), (z)))
#endif

// ---------------- prep: pack (x,y,z, sq) ----------------
__global__ __launch_bounds__(256) void k_prep(const float* __restrict__ xyz,
                                              float4* __restrict__ xyzw) {
  int t = blockIdx.x * 256 + threadIdx.x;
  if (t >= BB * NN) return;
  float x = xyz[t * 3 + 0], y = xyz[t * 3 + 1], z = xyz[t * 3 + 2];
  float sq = __fadd_rn(__fadd_rn(__fmul_rn(x, x), __fmul_rn(y, y)), __fmul_rn(z, z));
  xyzw[t] = make_float4(x, y, z, sq);
}

__device__ __forceinline__ float distf(const float4& q, const float4& c) {
  float dot = __fadd_rn(__fadd_rn(__fmul_rn(q.x, c.x), __fmul_rn(q.y, c.y)),
                        __fmul_rn(q.z, c.z));
  float d = __fsub_rn(__fadd_rn(q.w, c.w), __fmul_rn(2.0f, dot));
  return fmaxf(d, 0.0f);
}

// ---------------- KNN pass 1: two-phase (med3 value scan + index recovery) ------
__global__ __launch_bounds__(256) void k_knn1(const float4* __restrict__ xyzw,
                                              u32* __restrict__ cand_d,
                                              u32* __restrict__ cand_i) {
  __shared__ float4 pts[CHL];
  __shared__ u64 buf[4][64 * CAP];
  const int tid = threadIdx.x;
  const int bx = blockIdx.x;
  const int ch = blockIdx.y;
  const int b = bx / (NN / 256);
  const int n = (bx % (NN / 256)) * 256 + tid;
  const int m0 = ch * CHL;
  for (int i = tid; i < CHL; i += 256) pts[i] = xyzw[b * NN + m0 + i];
  const float4 q = xyzw[b * NN + n];
  __syncthreads();

  float a[KK];
#pragma unroll
  for (int i = 0; i < KK; ++i) a[i] = 3.4e38f;
#pragma unroll 2
  for (int mi = 0; mi < CHL; ++mi) {
    const float d = distf(q, pts[mi]);
#pragma unroll
    for (int i = KK - 1; i >= 1; --i) a[i] = MED3(d, a[i - 1], a[i]);
    a[0] = fminf(d, a[0]);
  }
  const float thr = a[KK - 1];

  u64* mybuf = &buf[tid >> 6][(tid & 63) * CAP];
  int cnt = 0;
  for (int mi = 0; mi < CHL; ++mi) {
    const float d = distf(q, pts[mi]);
    if (d <= thr) {
      if (cnt < CAP) mybuf[cnt] = ((u64)__float_as_uint(d) << 32) | (u32)(m0 + mi);
      ++cnt;
    }
  }

  double keys[KK];
#pragma unroll
  for (int i = 0; i < KK; ++i) keys[i] = __longlong_as_double(0x7FEFFFFFFFFFFFFFLL);
  if (cnt <= CAP) {
    for (int j = 0; j < cnt; ++j) {
      double kd = __longlong_as_double((long long)mybuf[j]);
      if (kd < keys[KK - 1]) {
#pragma unroll
        for (int i = 0; i < KK; ++i) {
          double lo = fmin(keys[i], kd);
          kd = fmax(keys[i], kd);
          keys[i] = lo;
        }
      }
    }
  } else {
    for (int mi = 0; mi < CHL; ++mi) {
      const float d = distf(q, pts[mi]);
      u64 kb_ = ((u64)__float_as_uint(d) << 32) | (u32)(m0 + mi);
      double kd = __longlong_as_double((long long)kb_);
      if (kd < keys[KK - 1]) {
#pragma unroll
        for (int i = 0; i < KK; ++i) {
          double lo = fmin(keys[i], kd);
          kd = fmax(keys[i], kd);
          keys[i] = lo;
        }
      }
    }
  }
  const int t = b * NN + n;
#pragma unroll
  for (int j = 0; j < KK; ++j) {
    u64 kk = (u64)__double_as_longlong(keys[j]);
    cand_d[(size_t)(ch * KK + j) * (BB * NN) + t] = (u32)(kk >> 32);
    cand_i[(size_t)(ch * KK + j) * (BB * NN) + t] = (u32)kk;
  }
}

// ---------------- KNN pass 2 ----------------
__global__ __launch_bounds__(128) void k_knn2(const u32* __restrict__ cand_d,
                                              const u32* __restrict__ cand_i,
                                              int* __restrict__ idx) {
  const int t = blockIdx.x * 128 + threadIdx.x;
  float a[KK];
#pragma unroll
  for (int i = 0; i < KK; ++i) a[i] = 3.4e38f;
#pragma unroll 4
  for (int i = 0; i < CHN * KK; ++i) {
    float d = __uint_as_float(cand_d[(size_t)i * (BB * NN) + t]);
#pragma unroll
    for (int s = KK - 1; s >= 1; --s) a[s] = MED3(d, a[s - 1], a[s]);
    a[0] = fminf(d, a[0]);
  }
  const float thr = a[KK - 1];
  double keys[KK];
#pragma unroll
  for (int i = 0; i < KK; ++i) keys[i] = __longlong_as_double(0x7FEFFFFFFFFFFFFFLL);
  for (int i = 0; i < CHN * KK; ++i) {
    u32 db = cand_d[(size_t)i * (BB * NN) + t];
    float d = __uint_as_float(db);
    if (d <= thr) {
      u64 kb_ = ((u64)db << 32) | (u64)cand_i[(size_t)i * (BB * NN) + t];
      double kd = __longlong_as_double((long long)kb_);
      if (kd < keys[KK - 1]) {
#pragma unroll
        for (int s = 0; s < KK; ++s) {
          double lo = fmin(keys[s], kd);
          kd = fmax(keys[s], kd);
          keys[s] = lo;
        }
      }
    }
  }
#pragma unroll
  for (int j = 0; j < KK; ++j)
    idx[t * KK + j] = (int)((u64)__double_as_longlong(keys[j]) & 0xffffffffu);
}

// ---------------- weight folding: Wd = aW1 @ Wsrc (torch [out,in] convention) ----
// grid 49 x 128 threads. Blocks 0..47: mat = bx/16, rows c0 = (bx%16)*8.
// Block 48: tvec[c] = sum_i aW1[c,i] * pb2[i].
__global__ __launch_bounds__(128) void k_fold(const float* __restrict__ aW1,
                                              const float* __restrict__ Wq,
                                              const float* __restrict__ Wk,
                                              const float* __restrict__ pW2,
                                              const float* __restrict__ pb2,
                                              float* __restrict__ WqA,
                                              float* __restrict__ WkA,
                                              float* __restrict__ WpA,
                                              float* __restrict__ tvec) {
  const int bx = blockIdx.x;
  const int j = threadIdx.x;
  if (bx == 48) {
    float s = 0.f;
    for (int i = 0; i < 128; ++i) s = fmaf(aW1[j * 128 + i], pb2[i], s);
    tvec[j] = s;
    return;
  }
  const int mat = bx >> 4;
  const int c0 = (bx & 15) * 8;
  const float* S = (mat == 0) ? Wq : (mat == 1) ? Wk : pW2;
  float* D = (mat == 0) ? WqA : (mat == 1) ? WkA : WpA;
  float acc[8];
#pragma unroll
  for (int r = 0; r < 8; ++r) acc[r] = 0.f;
  for (int i = 0; i < 128; ++i) {
    float sv = S[i * 128 + j];
#pragma unroll
    for (int r = 0; r < 8; ++r) acc[r] = fmaf(aW1[(c0 + r) * 128 + i], sv, acc[r]);
  }
#pragma unroll
  for (int r = 0; r < 8; ++r) D[(c0 + r) * 128 + j] = acc[r];
}

// ---------------- split-bf16 helpers ----------------
__device__ __forceinline__ void splitf(float a, ushort_t& h, ushort_t& l) {
  u32 ab = __float_as_uint(a);
  h = (ushort_t)(ab >> 16);
  float hif = __uint_as_float(ab & 0xffff0000u);
  l = (ushort_t)(__float_as_uint(a - hif) >> 16);
}

// pack W [128][128] fp32 -> frag-ordered split planes:
// po = T*2048 + s*128 + lr*8 + e ; c = T*16+lr, k = s*8+e
// grid 24 x 256: mat = bx/8, T = bx%8; thread handles 8 consecutive po.
__global__ __launch_bounds__(256) void k_packw(const float* __restrict__ S0,
                                               const float* __restrict__ S1,
                                               const float* __restrict__ S2,
                                               ushort_t* __restrict__ Phall,
                                               ushort_t* __restrict__ Plall) {
  const int bx = blockIdx.x;
  const int mat = bx >> 3;
  const int T = bx & 7;
  const float* S = (mat == 0) ? S0 : (mat == 1) ? S1 : S2;
  const int tid = threadIdx.x;
  const int s = tid >> 4;
  const int lr = tid & 15;
  const int c = T * 16 + lr;
  short8v vh, vl;
#pragma unroll
  for (int e = 0; e < 8; ++e) {
    ushort_t hh, ll;
    splitf(S[c * 128 + s * 8 + e], hh, ll);
    vh[e] = (short)hh;
    vl[e] = (short)ll;
  }
  const int po = mat * 16384 + T * 2048 + s * 128 + lr * 8;
  *(short8v*)&Phall[po] = vh;
  *(short8v*)&Plall[po] = vl;
}

// stage fp32 [128][128] matrix -> hi/lo bf16 planes in LDS, XOR-swizzled 16B slots
__device__ __forceinline__ void stage_mat(const float* __restrict__ G,
                                          ushort_t* Bh, ushort_t* Bl, int tid) {
  const float4* G4 = (const float4*)G;
#pragma unroll
  for (int i = 0; i < 16; ++i) {
    int f = i * 256 + tid;
    int r = f >> 5, k4 = f & 31;
    float4 v = G4[f];
    ushort_t h0, l0, h1, l1, h2, l2, h3, l3;
    splitf(v.x, h0, l0);
    splitf(v.y, h1, l1);
    splitf(v.z, h2, l2);
    splitf(v.w, h3, l3);
    int slot = k4 >> 1;
    int sub = (k4 & 1) * 4;
    int base = r * 128 + ((slot ^ (r & 15)) * 8) + sub;
    uint2 ph = make_uint2((u32)h0 | ((u32)h1 << 16), (u32)h2 | ((u32)h3 << 16));
    uint2 pl = make_uint2((u32)l0 | ((u32)l1 << 16), (u32)l2 | ((u32)l3 << 16));
    *(uint2*)&Bh[base] = ph;
    *(uint2*)&Bl[base] = pl;
  }
}

// LDS-A x LDS-W split GEMM (used by k_mm)
__device__ __forceinline__ void gemm128(const ushort_t* ABh, const ushort_t* ABl,
                                        const ushort_t* WBh, const ushort_t* WBl,
                                        f32x4 acc[4][4], int tid) {
  const int l = tid & 63, wid = tid >> 6;
  const int wrow = wid >> 1, wcol = wid & 1;
  const int lq = l >> 4, lr = l & 15;
#pragma unroll
  for (int ks = 0; ks < 4; ++ks) {
    const int sw8 = (((ks * 4 + lq) ^ lr) * 8);
    short8v ah[4], al[4], wh[4], wl[4];
#pragma unroll
    for (int rt = 0; rt < 4; ++rt) {
      int row = wrow * 64 + rt * 16 + lr;
      ah[rt] = *(const short8v*)&ABh[row * 128 + sw8];
      al[rt] = *(const short8v*)&ABl[row * 128 + sw8];
    }
#pragma unroll
    for (int ct = 0; ct < 4; ++ct) {
      int cc = wcol * 64 + ct * 16 + lr;
      wh[ct] = *(const short8v*)&WBh[cc * 128 + sw8];
      wl[ct] = *(const short8v*)&WBl[cc * 128 + sw8];
    }
#pragma unroll
    for (int rt = 0; rt < 4; ++rt)
#pragma unroll
      for (int ct = 0; ct < 4; ++ct) {
        acc[rt][ct] = __builtin_amdgcn_mfma_f32_16x16x32_bf16(ah[rt], wh[ct], acc[rt][ct], 0, 0, 0);
        acc[rt][ct] = __builtin_amdgcn_mfma_f32_16x16x32_bf16(ah[rt], wl[ct], acc[rt][ct], 0, 0, 0);
        acc[rt][ct] = __builtin_amdgcn_mfma_f32_16x16x32_bf16(al[rt], wh[ct], acc[rt][ct], 0, 0, 0);
      }
  }
}

// LDS-A x GLOBAL-packed-W split GEMM (used by k_fused; W streamed, L2-hot)
__device__ __forceinline__ void gemm128g(const ushort_t* ABh, const ushort_t* ABl,
                                         const ushort_t* __restrict__ Ph,
                                         const ushort_t* __restrict__ Pl,
                                         f32x4 acc[4][4], int tid) {
  const int l = tid & 63, wid = tid >> 6;
  const int wrow = wid >> 1, wcol = wid & 1;
  const int lq = l >> 4, lr = l & 15;
#pragma unroll
  for (int ks = 0; ks < 4; ++ks) {
    const int sw8 = (((ks * 4 + lq) ^ lr) * 8);
    short8v ah[4], al[4], wh[4], wl[4];
#pragma unroll
    for (int ct = 0; ct < 4; ++ct) {
      int off = (wcol * 4 + ct) * 2048 + (ks * 4 + lq) * 128 + lr * 8;
      wh[ct] = *(const short8v*)&Ph[off];
      wl[ct] = *(const short8v*)&Pl[off];
    }
#pragma unroll
    for (int rt = 0; rt < 4; ++rt) {
      int row = wrow * 64 + rt * 16 + lr;
      ah[rt] = *(const short8v*)&ABh[row * 128 + sw8];
      al[rt] = *(const short8v*)&ABl[row * 128 + sw8];
    }
#pragma unroll
    for (int rt = 0; rt < 4; ++rt)
#pragma unroll
      for (int ct = 0; ct < 4; ++ct) {
        acc[rt][ct] = __builtin_amdgcn_mfma_f32_16x16x32_bf16(ah[rt], wh[ct], acc[rt][ct], 0, 0, 0);
        acc[rt][ct] = __builtin_amdgcn_mfma_f32_16x16x32_bf16(ah[rt], wl[ct], acc[rt][ct], 0, 0, 0);
        acc[rt][ct] = __builtin_amdgcn_mfma_f32_16x16x32_bf16(al[rt], wh[ct], acc[rt][ct], 0, 0, 0);
      }
  }
}

// ---------------- plain GEMM: C[M,128] = A @ W^T (up to 3 weights share A) ------
template <int NW>
__global__ __launch_bounds__(256, 1) void k_mm(const float* __restrict__ A,
                                               const float* __restrict__ Wa,
                                               const float* __restrict__ Wb,
                                               const float* __restrict__ Wc,
                                               float* __restrict__ Ca,
                                               float* __restrict__ Cb,
                                               float* __restrict__ Cc) {
  __shared__ ushort_t ABh[128 * 128], ABl[128 * 128], WBh[128 * 128], WBl[128 * 128];
  const int tid = threadIdx.x;
  const int Rbase = blockIdx.x * 128;
  stage_mat(A + (size_t)Rbase * 128, ABh, ABl, tid);
  const int l = tid & 63, wid = tid >> 6;
  const int wrow = wid >> 1, wcol = wid & 1;
  const int lq = l >> 4, lr = l & 15;
  const float* Ws[3] = {Wa, Wb, Wc};
  float* Cs[3] = {Ca, Cb, Cc};
#pragma unroll
  for (int w = 0; w < NW; ++w) {
    if (w) __syncthreads();
    stage_mat(Ws[w], WBh, WBl, tid);
    __syncthreads();
    f32x4 acc[4][4];
#pragma unroll
    for (int rt = 0; rt < 4; ++rt)
#pragma unroll
      for (int ct = 0; ct < 4; ++ct) acc[rt][ct] = (f32x4)0.f;
    gemm128(ABh, ABl, WBh, WBl, acc, tid);
#pragma unroll
    for (int rt = 0; rt < 4; ++rt)
#pragma unroll
      for (int ct = 0; ct < 4; ++ct) {
        int c = wcol * 64 + ct * 16 + lr;
#pragma unroll
        for (int reg = 0; reg < 4; ++reg) {
          int R = Rbase + wrow * 64 + rt * 16 + lq * 4 + reg;
          Cs[w][(size_t)R * 128 + c] = acc[rt][ct][reg];
        }
      }
  }
}

// ---------------- fused chain (folded): h1 -> {pos, posA} -> z -> logits -> out --
// Wpk planes: mat0 = pW2, mat1 = WpA (= aW1@pW2), mat2 = aW2.
__global__ __launch_bounds__(256, 2) void k_fused(
    const float4* __restrict__ xyzw, const int* __restrict__ idx,
    const float* __restrict__ qbA, const float* __restrict__ kbA,
    const float* __restrict__ vb, const float* __restrict__ pW1,
    const float* __restrict__ pb1, const float* __restrict__ pg,
    const float* __restrict__ pbeta, const float* __restrict__ pm,
    const float* __restrict__ pv, const float* __restrict__ pb2,
    const float* __restrict__ ab1, const float* __restrict__ ag,
    const float* __restrict__ abeta, const float* __restrict__ am,
    const float* __restrict__ av, const float* __restrict__ ab2,
    const float* __restrict__ tvec, const ushort_t* __restrict__ Phall,
    const ushort_t* __restrict__ Plall, float* __restrict__ outb) {
  __shared__ ushort_t ABh[128 * 128], ABl[128 * 128];
  __shared__ float4 fW1[128];
  __shared__ float sA[128], tA[128], pB2[128], aB2[128];
  __shared__ int idxs[128];
  const int tid = threadIdx.x;
  const int Qbase = blockIdx.x * 8;
  const int b = Qbase >> 13;

  if (tid < 128) {
    int c = tid;
    idxs[c] = idx[Qbase * KK + c];
    float s1 = pg[c] / sqrtf(pv[c] + EPSV);
    fW1[c] = make_float4(pW1[c * 3] * s1, pW1[c * 3 + 1] * s1, pW1[c * 3 + 2] * s1,
                         (pb1[c] - pm[c]) * s1 + pbeta[c]);
    float s2 = ag[c] / sqrtf(av[c] + EPSV);
    sA[c] = s2;
    tA[c] = fmaf(s2, ab1[c] + tvec[c] - am[c], abeta[c]);
    pB2[c] = pb2[c];
    aB2[c] = ab2[c];
  }
  __syncthreads();

  // h1 tile -> A planes (packed 16B writes)
  {
    int r = tid >> 1, chalf = tid & 1;
    int Q = Qbase + (r >> 4);
    int m = idxs[(r >> 4) * 16 + (r & 15)];
    float4 pq = xyzw[Q];
    float4 pn = xyzw[b * NN + m];
    float rx = pn.x - pq.x, ry = pn.y - pq.y, rz = pn.z - pq.z;
#pragma unroll
    for (int g = 0; g < 8; ++g) {
      short8v vh, vl;
      int c0 = chalf * 64 + g * 8;
#pragma unroll
      for (int e = 0; e < 8; ++e) {
        float4 w = fW1[c0 + e];
        float h = fmaxf(fmaf(rz, w.z, fmaf(ry, w.y, fmaf(rx, w.x, w.w))), 0.f);
        ushort_t hh, ll;
        splitf(h, hh, ll);
        vh[e] = (short)hh;
        vl[e] = (short)ll;
      }
      int sw = (chalf * 8 + g) ^ (r & 15);
      *(short8v*)&ABh[r * 128 + sw * 8] = vh;
      *(short8v*)&ABl[r * 128 + sw * 8] = vl;
    }
  }
  __syncthreads();

  const int l = tid & 63, wid = tid >> 6;
  const int wrow = wid >> 1, wcol = wid & 1;
  const int lq = l >> 4, lr = l & 15;

  // GEMM0a: pos = h1 @ pW2^T (held); GEMM0b: posA = h1 @ WpA^T (held)
  f32x4 pos_[4][4], pa_[4][4];
#pragma unroll
  for (int rt = 0; rt < 4; ++rt)
#pragma unroll
    for (int ct = 0; ct < 4; ++ct) {
      pos_[rt][ct] = (f32x4)0.f;
      pa_[rt][ct] = (f32x4)0.f;
    }
  gemm128g(ABh, ABl, Phall, Plall, pos_, tid);
  gemm128g(ABh, ABl, Phall + 16384, Plall + 16384, pa_, tid);
  __syncthreads();

  // z = relu(s * (qA_gather - kA_gather + posA) + t) -> A planes
#pragma unroll
  for (int rt = 0; rt < 4; ++rt) {
    int qi_loc = wrow * 4 + rt;
    int Q = Qbase + qi_loc;
    int mr[4];
#pragma unroll
    for (int reg = 0; reg < 4; ++reg) mr[reg] = b * NN + idxs[qi_loc * 16 + lq * 4 + reg];
#pragma unroll
    for (int ct = 0; ct < 4; ++ct) {
      int c = wcol * 64 + ct * 16 + lr;
      float qv = qbA[(size_t)Q * 128 + c];
      float sc = sA[c], tc = tA[c];
#pragma unroll
      for (int reg = 0; reg < 4; ++reg) {
        float u = qv - kbA[(size_t)mr[reg] * 128 + c] + pa_[rt][ct][reg];
        float z = fmaxf(fmaf(u, sc, tc), 0.f);
        ushort_t hh, ll;
        splitf(z, hh, ll);
        int R15 = lq * 4 + reg;
        int row = wrow * 64 + rt * 16 + R15;
        int base = row * 128 + (((c >> 3) ^ R15) * 8) + (c & 7);
        ABh[base] = hh;
        ABl[base] = ll;
      }
    }
  }
  __syncthreads();

  // GEMM2: logits = z @ aW2^T (+ab2); softmax over 16 neighbors; combine
  f32x4 acc[4][4];
#pragma unroll
  for (int rt = 0; rt < 4; ++rt)
#pragma unroll
    for (int ct = 0; ct < 4; ++ct) acc[rt][ct] = (f32x4)0.f;
  gemm128g(ABh, ABl, Phall + 32768, Plall + 32768, acc, tid);

#pragma unroll
  for (int rt = 0; rt < 4; ++rt) {
    int qi_loc = wrow * 4 + rt;
    int Q = Qbase + qi_loc;
    int mr[4];
#pragma unroll
    for (int reg = 0; reg < 4; ++reg) mr[reg] = b * NN + idxs[qi_loc * 16 + lq * 4 + reg];
#pragma unroll
    for (int ct = 0; ct < 4; ++ct) {
      int c = wcol * 64 + ct * 16 + lr;
      float ab2v = aB2[c];
      float lg[4];
#pragma unroll
      for (int reg = 0; reg < 4; ++reg) lg[reg] = acc[rt][ct][reg] + ab2v;
      float mx = fmaxf(fmaxf(lg[0], lg[1]), fmaxf(lg[2], lg[3]));
      mx = fmaxf(mx, __shfl_xor(mx, 16));
      mx = fmaxf(mx, __shfl_xor(mx, 32));
      float s = 0.f, o = 0.f;
      float pb2v = pB2[c];
#pragma unroll
      for (int reg = 0; reg < 4; ++reg) {
        float e_ = expf(lg[reg] - mx);
        s += e_;
        float vv = vb[(size_t)mr[reg] * 128 + c] + pos_[rt][ct][reg] + pb2v;
        o = fmaf(e_, vv, o);
      }
      s += __shfl_xor(s, 16);
      s += __shfl_xor(s, 32);
      o += __shfl_xor(o, 16);
      o += __shfl_xor(o, 32);
      if (lq == 0) outb[(size_t)Q * 128 + c] = o / s;
    }
  }
}

// ---------------- host launch ----------------
extern "C" void kernel_launch(void* const* d_in, const int* in_sizes, int n_in,
                              void* d_out, int out_size, void* d_ws, size_t ws_size,
                              hipStream_t stream) {
  const float* xyz = (const float*)d_in[0];
  const float* feat = (const float*)d_in[1];
  const float* Wq = (const float*)d_in[2];
  const float* Wk = (const float*)d_in[3];
  const float* Wv = (const float*)d_in[4];
  const float* pW1 = (const float*)d_in[5];
  const float* pb1 = (const float*)d_in[6];
  const float* pg = (const float*)d_in[7];
  const float* pbeta = (const float*)d_in[8];
  const float* pmean = (const float*)d_in[9];
  const float* pvar = (const float*)d_in[10];
  const float* pW2 = (const float*)d_in[11];
  const float* pb2 = (const float*)d_in[12];
  const float* aW1 = (const float*)d_in[13];
  const float* ab1 = (const float*)d_in[14];
  const float* ag = (const float*)d_in[15];
  const float* abeta = (const float*)d_in[16];
  const float* amean = (const float*)d_in[17];
  const float* avar = (const float*)d_in[18];
  const float* aW2 = (const float*)d_in[19];
  const float* ab2 = (const float*)d_in[20];
  const float* Wout = (const float*)d_in[21];
  float* out = (float*)d_out;
  char* ws = (char*)d_ws;

  size_t off = 0;
  auto alloc = [&](size_t bytes) {
    size_t r = off;
    off += (bytes + 255) & ~(size_t)255;
    return r;
  };
  float4* xyzw = (float4*)(ws + alloc((size_t)BB * NN * 16));
  int* idx = (int*)(ws + alloc((size_t)BB * NN * KK * 4));
  size_t o_qb = alloc((size_t)BB * NN * CC * 4);
  size_t o_kb = alloc((size_t)BB * NN * CC * 4);
  size_t o_vb = alloc((size_t)BB * NN * CC * 4);
  size_t o_ob = alloc((size_t)BB * NN * CC * 4);
  float* qbA = (float*)(ws + o_qb);
  float* kbA = (float*)(ws + o_kb);
  float* vb = (float*)(ws + o_vb);
  float* outb = (float*)(ws + o_ob);
  // KNN candidate SoA planes (16 MB each) alias qbA..outb (dead until after knn2).
  u32* cand_d = (u32*)(ws + o_qb);
  u32* cand_i = (u32*)(ws + o_vb);
  // folded weights + packed split planes (live whole run; past the 34.3 MB base)
  float* WqA = (float*)(ws + alloc(128 * 128 * 4));
  float* WkA = (float*)(ws + alloc(128 * 128 * 4));
  float* WpA = (float*)(ws + alloc(128 * 128 * 4));
  float* tvec = (float*)(ws + alloc(128 * 4));
  ushort_t* Phall = (ushort_t*)(ws + alloc(3 * 16384 * 2));
  ushort_t* Plall = (ushort_t*)(ws + alloc(3 * 16384 * 2));

  k_prep<<<(BB * NN) / 256, 256, 0, stream>>>(xyz, xyzw);
  k_fold<<<49, 128, 0, stream>>>(aW1, Wq, Wk, pW2, pb2, WqA, WkA, WpA, tvec);
  k_packw<<<24, 256, 0, stream>>>(pW2, WpA, aW2, Phall, Plall);

  k_knn1<<<dim3((BB * NN) / 256, CHN), 256, 0, stream>>>(xyzw, cand_d, cand_i);
  k_knn2<<<(BB * NN) / 128, 128, 0, stream>>>(cand_d, cand_i, idx);

  k_mm<3><<<(BB * NN) / 128, 256, 0, stream>>>(feat, WqA, WkA, Wv, qbA, kbA, vb);

  k_fused<<<(BB * NN * KK) / 128, 256, 0, stream>>>(
      xyzw, idx, qbA, kbA, vb, pW1, pb1, pg, pbeta, pmean, pvar, pb2, ab1, ag,
      abeta, amean, avar, ab2, tvec, Phall, Plall, outb);

  k_mm<1><<<(BB * NN) / 128, 256, 0, stream>>>(outb, Wout, nullptr, nullptr, out,
                                               nullptr, nullptr);
}

// Round 6
// 393.221 us; speedup vs baseline: 3.3696x; 1.1130x over previous
//
#include <hip/hip_runtime.h>
#include <cstdint>
#include <cstddef>

#define BB 2
#define NN 8192
#define CC 128
#define KK 16
#define CHN 16
#define CHL (NN / CHN)
#define EPSV 1e-5f
#define CAP 24

typedef unsigned long long u64;
typedef unsigned int u32;
typedef unsigned short ushort_t;
typedef short short8v __attribute__((ext_vector_type(8)));
typedef float f32x4 __attribute__((ext_vector_type(4)));

// real v_med3_f32 (2-cyc VOP3) — the __has_builtin(fmed3f) path never fired (R5
// measured ~85 insts/cand == the 4-op fallback; asm guarantees the single op).
__device__ __forceinline__ float med3f(float x, float y, float z) {
  float r;
  asm("v_med3_f32 %0, %1, %2, %3" : "=v"(r) : "v"(x), "v"(y), "v"(z));
  return r;
}

// ---------------- prep: pack (x,y,z, sq) ----------------
__global__ __launch_bounds__(256) void k_prep(const float* __restrict__ xyz,
                                              float4* __restrict__ xyzw) {
  int t = blockIdx.x * 256 + threadIdx.x;
  if (t >= BB * NN) return;
  float x = xyz[t * 3 + 0], y = xyz[t * 3 + 1], z = xyz[t * 3 + 2];
  float sq = __fadd_rn(__fadd_rn(__fmul_rn(x, x), __fmul_rn(y, y)), __fmul_rn(z, z));
  xyzw[t] = make_float4(x, y, z, sq);
}

__device__ __forceinline__ float distf(const float4& q, const float4& c) {
  float dot = __fadd_rn(__fadd_rn(__fmul_rn(q.x, c.x), __fmul_rn(q.y, c.y)),
                        __fmul_rn(q.z, c.z));
  float d = __fsub_rn(__fadd_rn(q.w, c.w), __fmul_rn(2.0f, dot));
  return fmaxf(d, 0.0f);
}

// ---------------- KNN pass 1: med3 value scan + index recovery ----------------
__global__ __launch_bounds__(256) void k_knn1(const float4* __restrict__ xyzw,
                                              u32* __restrict__ cand_d,
                                              u32* __restrict__ cand_i) {
  __shared__ float4 pts[CHL];
  __shared__ u32 buf[4][64 * CAP];
  const int tid = threadIdx.x;
  const int bx = blockIdx.x;
  const int ch = blockIdx.y;
  const int b = bx / (NN / 256);
  const int n = (bx % (NN / 256)) * 256 + tid;
  const int m0 = ch * CHL;
  for (int i = tid; i < CHL; i += 256) pts[i] = xyzw[b * NN + m0 + i];
  const float4 q = xyzw[b * NN + n];
  __syncthreads();

  // phase 1: exact smallest-16 VALUES, branchless med3 ripple (1 op/slot)
  float a[KK];
#pragma unroll
  for (int i = 0; i < KK; ++i) a[i] = 3.4e38f;
#pragma unroll 2
  for (int mi = 0; mi < CHL; ++mi) {
    const float d = distf(q, pts[mi]);
#pragma unroll
    for (int i = KK - 1; i >= 1; --i) a[i] = med3f(d, a[i - 1], a[i]);
    a[0] = fminf(d, a[0]);
  }
  const float thr = a[KK - 1];  // exact 16th-smallest distance in chunk

  // phase 2: collect chunk-local indices with d <= thr (>=16, usually ==16)
  u32* mybuf = &buf[tid >> 6][(tid & 63) * CAP];
  int cnt = 0;
  for (int mi = 0; mi < CHL; ++mi) {
    const float d = distf(q, pts[mi]);
    if (d <= thr) {
      if (cnt < CAP) mybuf[cnt] = (u32)mi;
      ++cnt;
    }
  }

  // merge: exact (dist, idx) lexicographic top-16 (f64-bit-order trick)
  double keys[KK];
#pragma unroll
  for (int i = 0; i < KK; ++i) keys[i] = __longlong_as_double(0x7FEFFFFFFFFFFFFFLL);
  if (cnt <= CAP) {
    for (int j = 0; j < cnt; ++j) {
      int m = (int)mybuf[j];
      const float d = distf(q, pts[m]);
      u64 kb_ = ((u64)__float_as_uint(d) << 32) | (u32)(m0 + m);
      double kd = __longlong_as_double((long long)kb_);
      if (kd < keys[KK - 1]) {
#pragma unroll
        for (int i = 0; i < KK; ++i) {
          double lo = fmin(keys[i], kd);
          kd = fmax(keys[i], kd);
          keys[i] = lo;
        }
      }
    }
  } else {
    // pathological tie overflow: exact full rescan (never for random data)
    for (int mi = 0; mi < CHL; ++mi) {
      const float d = distf(q, pts[mi]);
      u64 kb_ = ((u64)__float_as_uint(d) << 32) | (u32)(m0 + mi);
      double kd = __longlong_as_double((long long)kb_);
      if (kd < keys[KK - 1]) {
#pragma unroll
        for (int i = 0; i < KK; ++i) {
          double lo = fmin(keys[i], kd);
          kd = fmax(keys[i], kd);
          keys[i] = lo;
        }
      }
    }
  }
  const int t = b * NN + n;
#pragma unroll
  for (int j = 0; j < KK; ++j) {
    u64 kk = (u64)__double_as_longlong(keys[j]);
    cand_d[(size_t)(ch * KK + j) * (BB * NN) + t] = (u32)(kk >> 32);
    cand_i[(size_t)(ch * KK + j) * (BB * NN) + t] = (u32)kk;
  }
}

// ---------------- KNN pass 2 ----------------
__global__ __launch_bounds__(128) void k_knn2(const u32* __restrict__ cand_d,
                                              const u32* __restrict__ cand_i,
                                              int* __restrict__ idx) {
  const int t = blockIdx.x * 128 + threadIdx.x;
  float a[KK];
#pragma unroll
  for (int i = 0; i < KK; ++i) a[i] = 3.4e38f;
#pragma unroll 4
  for (int i = 0; i < CHN * KK; ++i) {
    float d = __uint_as_float(cand_d[(size_t)i * (BB * NN) + t]);
#pragma unroll
    for (int s = KK - 1; s >= 1; --s) a[s] = med3f(d, a[s - 1], a[s]);
    a[0] = fminf(d, a[0]);
  }
  const float thr = a[KK - 1];
  double keys[KK];
#pragma unroll
  for (int i = 0; i < KK; ++i) keys[i] = __longlong_as_double(0x7FEFFFFFFFFFFFFFLL);
  for (int i = 0; i < CHN * KK; ++i) {
    u32 db = cand_d[(size_t)i * (BB * NN) + t];
    float d = __uint_as_float(db);
    if (d <= thr) {
      u64 kb_ = ((u64)db << 32) | (u64)cand_i[(size_t)i * (BB * NN) + t];
      double kd = __longlong_as_double((long long)kb_);
      if (kd < keys[KK - 1]) {
#pragma unroll
        for (int s = 0; s < KK; ++s) {
          double lo = fmin(keys[s], kd);
          kd = fmax(keys[s], kd);
          keys[s] = lo;
        }
      }
    }
  }
#pragma unroll
  for (int j = 0; j < KK; ++j)
    idx[t * KK + j] = (int)((u64)__double_as_longlong(keys[j]) & 0xffffffffu);
}

// ---------------- weight folding: Wd = aW1 @ Wsrc ----------------
__global__ __launch_bounds__(128) void k_fold(const float* __restrict__ aW1,
                                              const float* __restrict__ Wq,
                                              const float* __restrict__ Wk,
                                              const float* __restrict__ pW2,
                                              const float* __restrict__ pb2,
                                              float* __restrict__ WqA,
                                              float* __restrict__ WkA,
                                              float* __restrict__ WpA,
                                              float* __restrict__ tvec) {
  const int bx = blockIdx.x;
  const int j = threadIdx.x;
  if (bx == 48) {
    float s = 0.f;
    for (int i = 0; i < 128; ++i) s = fmaf(aW1[j * 128 + i], pb2[i], s);
    tvec[j] = s;
    return;
  }
  const int mat = bx >> 4;
  const int c0 = (bx & 15) * 8;
  const float* S = (mat == 0) ? Wq : (mat == 1) ? Wk : pW2;
  float* D = (mat == 0) ? WqA : (mat == 1) ? WkA : WpA;
  float acc[8];
#pragma unroll
  for (int r = 0; r < 8; ++r) acc[r] = 0.f;
  for (int i = 0; i < 128; ++i) {
    float sv = S[i * 128 + j];
#pragma unroll
    for (int r = 0; r < 8; ++r) acc[r] = fmaf(aW1[(c0 + r) * 128 + i], sv, acc[r]);
  }
#pragma unroll
  for (int r = 0; r < 8; ++r) D[(c0 + r) * 128 + j] = acc[r];
}

// ---------------- split-bf16 helpers ----------------
__device__ __forceinline__ void splitf(float a, ushort_t& h, ushort_t& l) {
  u32 ab = __float_as_uint(a);
  h = (ushort_t)(ab >> 16);
  float hif = __uint_as_float(ab & 0xffff0000u);
  l = (ushort_t)(__float_as_uint(a - hif) >> 16);
}

// pack W [128][128] fp32 -> frag-ordered split planes (7 matrices):
// po = mat*16384 + T*2048 + s*128 + lr*8 + e ; c = T*16+lr, k = s*8+e
__global__ __launch_bounds__(256) void k_packw(
    const float* __restrict__ S0, const float* __restrict__ S1,
    const float* __restrict__ S2, const float* __restrict__ S3,
    const float* __restrict__ S4, const float* __restrict__ S5,
    const float* __restrict__ S6, ushort_t* __restrict__ Phall,
    ushort_t* __restrict__ Plall) {
  const int bx = blockIdx.x;
  const int mat = bx >> 3;
  const int T = bx & 7;
  const float* S;
  switch (mat) {
    case 0: S = S0; break;
    case 1: S = S1; break;
    case 2: S = S2; break;
    case 3: S = S3; break;
    case 4: S = S4; break;
    case 5: S = S5; break;
    default: S = S6; break;
  }
  const int tid = threadIdx.x;
  const int s = tid >> 4;
  const int lr = tid & 15;
  const int c = T * 16 + lr;
  short8v vh, vl;
#pragma unroll
  for (int e = 0; e < 8; ++e) {
    ushort_t hh, ll;
    splitf(S[c * 128 + s * 8 + e], hh, ll);
    vh[e] = (short)hh;
    vl[e] = (short)ll;
  }
  const int po = mat * 16384 + T * 2048 + s * 128 + lr * 8;
  *(short8v*)&Phall[po] = vh;
  *(short8v*)&Plall[po] = vl;
}

// stage R rows x 128 cols fp32 -> hi/lo bf16 planes in LDS, XOR-swizzled
template <int ITERS>
__device__ __forceinline__ void stage_rows(const float4* __restrict__ G4,
                                           ushort_t* Bh, ushort_t* Bl, int tid) {
#pragma unroll
  for (int i = 0; i < ITERS; ++i) {
    int f = i * 256 + tid;
    int r = f >> 5, k4 = f & 31;
    float4 v = G4[f];
    ushort_t h0, l0, h1, l1, h2, l2, h3, l3;
    splitf(v.x, h0, l0);
    splitf(v.y, h1, l1);
    splitf(v.z, h2, l2);
    splitf(v.w, h3, l3);
    int slot = k4 >> 1;
    int sub = (k4 & 1) * 4;
    int base = r * 128 + ((slot ^ (r & 15)) * 8) + sub;
    *(uint2*)&Bh[base] = make_uint2((u32)h0 | ((u32)h1 << 16), (u32)h2 | ((u32)h3 << 16));
    *(uint2*)&Bl[base] = make_uint2((u32)l0 | ((u32)l1 << 16), (u32)l2 | ((u32)l3 << 16));
  }
}

// 64-row LDS-A x GLOBAL-packed-W split GEMM (k_fused)
__device__ __forceinline__ void gemm64g(const ushort_t* ABh, const ushort_t* ABl,
                                        const ushort_t* __restrict__ Ph,
                                        const ushort_t* __restrict__ Pl,
                                        f32x4 acc[2][4], int tid) {
  const int l = tid & 63, wid = tid >> 6;
  const int wrow = wid >> 1, wcol = wid & 1;
  const int lq = l >> 4, lr = l & 15;
#pragma unroll
  for (int ks = 0; ks < 4; ++ks) {
    const int sw8 = (((ks * 4 + lq) ^ lr) * 8);
    short8v ah[2], al[2], wh[4], wl[4];
#pragma unroll
    for (int ct = 0; ct < 4; ++ct) {
      int off = (wcol * 4 + ct) * 2048 + (ks * 4 + lq) * 128 + lr * 8;
      wh[ct] = *(const short8v*)&Ph[off];
      wl[ct] = *(const short8v*)&Pl[off];
    }
#pragma unroll
    for (int rt = 0; rt < 2; ++rt) {
      int row = wrow * 32 + rt * 16 + lr;
      ah[rt] = *(const short8v*)&ABh[row * 128 + sw8];
      al[rt] = *(const short8v*)&ABl[row * 128 + sw8];
    }
#pragma unroll
    for (int rt = 0; rt < 2; ++rt)
#pragma unroll
      for (int ct = 0; ct < 4; ++ct) {
        acc[rt][ct] = __builtin_amdgcn_mfma_f32_16x16x32_bf16(ah[rt], wh[ct], acc[rt][ct], 0, 0, 0);
        acc[rt][ct] = __builtin_amdgcn_mfma_f32_16x16x32_bf16(ah[rt], wl[ct], acc[rt][ct], 0, 0, 0);
        acc[rt][ct] = __builtin_amdgcn_mfma_f32_16x16x32_bf16(al[rt], wh[ct], acc[rt][ct], 0, 0, 0);
      }
  }
}

// ---------------- 32-row GEMM, W streamed from packed planes ----------------
template <int NW>
__global__ __launch_bounds__(256) void k_mms(const float* __restrict__ A,
                                             const ushort_t* __restrict__ Phall,
                                             const ushort_t* __restrict__ Plall,
                                             int m0, float* __restrict__ C0,
                                             float* __restrict__ C1,
                                             float* __restrict__ C2) {
  __shared__ ushort_t ABh[32 * 128], ABl[32 * 128];
  const int tid = threadIdx.x;
  const int Rbase = blockIdx.x * 32;
  stage_rows<4>((const float4*)(A + (size_t)Rbase * 128), ABh, ABl, tid);
  __syncthreads();
  const int l = tid & 63, wid = tid >> 6;
  const int lq = l >> 4, lr = l & 15;
  float* Cs[3] = {C0, C1, C2};
#pragma unroll
  for (int w = 0; w < NW; ++w) {
    const ushort_t* Ph = Phall + (size_t)(m0 + w) * 16384;
    const ushort_t* Pl = Plall + (size_t)(m0 + w) * 16384;
    f32x4 acc[2][2];
#pragma unroll
    for (int rt = 0; rt < 2; ++rt)
#pragma unroll
      for (int ct = 0; ct < 2; ++ct) acc[rt][ct] = (f32x4)0.f;
#pragma unroll
    for (int ks = 0; ks < 4; ++ks) {
      const int sw8 = (((ks * 4 + lq) ^ lr) * 8);
      short8v ah[2], al[2], wh[2], wl[2];
#pragma unroll
      for (int ct = 0; ct < 2; ++ct) {
        int off = (wid * 2 + ct) * 2048 + (ks * 4 + lq) * 128 + lr * 8;
        wh[ct] = *(const short8v*)&Ph[off];
        wl[ct] = *(const short8v*)&Pl[off];
      }
#pragma unroll
      for (int rt = 0; rt < 2; ++rt) {
        int row = rt * 16 + lr;
        ah[rt] = *(const short8v*)&ABh[row * 128 + sw8];
        al[rt] = *(const short8v*)&ABl[row * 128 + sw8];
      }
#pragma unroll
      for (int rt = 0; rt < 2; ++rt)
#pragma unroll
        for (int ct = 0; ct < 2; ++ct) {
          acc[rt][ct] = __builtin_amdgcn_mfma_f32_16x16x32_bf16(ah[rt], wh[ct], acc[rt][ct], 0, 0, 0);
          acc[rt][ct] = __builtin_amdgcn_mfma_f32_16x16x32_bf16(ah[rt], wl[ct], acc[rt][ct], 0, 0, 0);
          acc[rt][ct] = __builtin_amdgcn_mfma_f32_16x16x32_bf16(al[rt], wh[ct], acc[rt][ct], 0, 0, 0);
        }
    }
#pragma unroll
    for (int rt = 0; rt < 2; ++rt)
#pragma unroll
      for (int ct = 0; ct < 2; ++ct) {
        int c = (wid * 2 + ct) * 16 + lr;
#pragma unroll
        for (int reg = 0; reg < 4; ++reg) {
          int R = Rbase + rt * 16 + lq * 4 + reg;
          Cs[w][(size_t)R * 128 + c] = acc[rt][ct][reg];
        }
      }
  }
}

// ---------------- fused chain (64 rows / 4 queries per block) ----------------
// Planes: mat0 = pW2, mat1 = WpA (= aW1@pW2), mat2 = aW2.
__global__ __launch_bounds__(256, 3) void k_fused(
    const float4* __restrict__ xyzw, const int* __restrict__ idx,
    const float* __restrict__ qbA, const float* __restrict__ kbA,
    const float* __restrict__ vb, const float* __restrict__ pW1,
    const float* __restrict__ pb1, const float* __restrict__ pg,
    const float* __restrict__ pbeta, const float* __restrict__ pm,
    const float* __restrict__ pv, const float* __restrict__ pb2,
    const float* __restrict__ ab1, const float* __restrict__ ag,
    const float* __restrict__ abeta, const float* __restrict__ am,
    const float* __restrict__ av, const float* __restrict__ ab2,
    const float* __restrict__ tvec, const ushort_t* __restrict__ Phall,
    const ushort_t* __restrict__ Plall, float* __restrict__ outb) {
  __shared__ ushort_t ABh[64 * 128], ABl[64 * 128];
  __shared__ float4 fW1[128];
  __shared__ float sA[128], tA[128], pB2[128], aB2[128];
  __shared__ int idxs[64];
  const int tid = threadIdx.x;
  const int Qbase = blockIdx.x * 4;
  const int b = Qbase >> 13;

  if (tid < 64) idxs[tid] = idx[Qbase * KK + tid];
  if (tid < 128) {
    int c = tid;
    float s1 = pg[c] / sqrtf(pv[c] + EPSV);
    fW1[c] = make_float4(pW1[c * 3] * s1, pW1[c * 3 + 1] * s1, pW1[c * 3 + 2] * s1,
                         (pb1[c] - pm[c]) * s1 + pbeta[c]);
    float s2 = ag[c] / sqrtf(av[c] + EPSV);
    sA[c] = s2;
    tA[c] = fmaf(s2, ab1[c] + tvec[c] - am[c], abeta[c]);
    pB2[c] = pb2[c];
    aB2[c] = ab2[c];
  }
  __syncthreads();

  // h1 tile (64 rows) -> A planes
  {
    int r = tid >> 2, qq = tid & 3;
    int Q = Qbase + (r >> 4);
    int m = idxs[r];
    float4 pq = xyzw[Q];
    float4 pn = xyzw[b * NN + m];
    float rx = pn.x - pq.x, ry = pn.y - pq.y, rz = pn.z - pq.z;
#pragma unroll
    for (int g = 0; g < 4; ++g) {
      short8v vh, vl;
      int c0 = qq * 32 + g * 8;
#pragma unroll
      for (int e = 0; e < 8; ++e) {
        float4 w = fW1[c0 + e];
        float h = fmaxf(fmaf(rz, w.z, fmaf(ry, w.y, fmaf(rx, w.x, w.w))), 0.f);
        ushort_t hh, ll;
        splitf(h, hh, ll);
        vh[e] = (short)hh;
        vl[e] = (short)ll;
      }
      int sw = (c0 >> 3) ^ (r & 15);
      *(short8v*)&ABh[r * 128 + sw * 8] = vh;
      *(short8v*)&ABl[r * 128 + sw * 8] = vl;
    }
  }
  __syncthreads();

  const int l = tid & 63, wid = tid >> 6;
  const int wrow = wid >> 1, wcol = wid & 1;
  const int lq = l >> 4, lr = l & 15;

  // GEMM0a: pos = h1 @ pW2^T (held); GEMM0b: posA = h1 @ WpA^T (held)
  f32x4 pos_[2][4], pa_[2][4];
#pragma unroll
  for (int rt = 0; rt < 2; ++rt)
#pragma unroll
    for (int ct = 0; ct < 4; ++ct) {
      pos_[rt][ct] = (f32x4)0.f;
      pa_[rt][ct] = (f32x4)0.f;
    }
  gemm64g(ABh, ABl, Phall, Plall, pos_, tid);
  gemm64g(ABh, ABl, Phall + 16384, Plall + 16384, pa_, tid);
  __syncthreads();

  // z = relu(s * (qA_gather - kA_gather + posA) + t) -> A planes
#pragma unroll
  for (int rt = 0; rt < 2; ++rt) {
    int qi_loc = wrow * 2 + rt;
    int Q = Qbase + qi_loc;
    int mr[4];
#pragma unroll
    for (int reg = 0; reg < 4; ++reg) mr[reg] = b * NN + idxs[qi_loc * 16 + lq * 4 + reg];
#pragma unroll
    for (int ct = 0; ct < 4; ++ct) {
      int c = wcol * 64 + ct * 16 + lr;
      float qv = qbA[(size_t)Q * 128 + c];
      float sc = sA[c], tc = tA[c];
#pragma unroll
      for (int reg = 0; reg < 4; ++reg) {
        float u = qv - kbA[(size_t)mr[reg] * 128 + c] + pa_[rt][ct][reg];
        float z = fmaxf(fmaf(u, sc, tc), 0.f);
        ushort_t hh, ll;
        splitf(z, hh, ll);
        int R15 = lq * 4 + reg;
        int row = wrow * 32 + rt * 16 + R15;
        int base = row * 128 + (((c >> 3) ^ R15) * 8) + (c & 7);
        ABh[base] = hh;
        ABl[base] = ll;
      }
    }
  }
  __syncthreads();

  // GEMM2: logits = z @ aW2^T (+ab2); softmax over 16 neighbors; combine
  f32x4 acc[2][4];
#pragma unroll
  for (int rt = 0; rt < 2; ++rt)
#pragma unroll
    for (int ct = 0; ct < 4; ++ct) acc[rt][ct] = (f32x4)0.f;
  gemm64g(ABh, ABl, Phall + 32768, Plall + 32768, acc, tid);

#pragma unroll
  for (int rt = 0; rt < 2; ++rt) {
    int qi_loc = wrow * 2 + rt;
    int Q = Qbase + qi_loc;
    int mr[4];
#pragma unroll
    for (int reg = 0; reg < 4; ++reg) mr[reg] = b * NN + idxs[qi_loc * 16 + lq * 4 + reg];
#pragma unroll
    for (int ct = 0; ct < 4; ++ct) {
      int c = wcol * 64 + ct * 16 + lr;
      float ab2v = aB2[c];
      float lg[4];
#pragma unroll
      for (int reg = 0; reg < 4; ++reg) lg[reg] = acc[rt][ct][reg] + ab2v;
      float mx = fmaxf(fmaxf(lg[0], lg[1]), fmaxf(lg[2], lg[3]));
      mx = fmaxf(mx, __shfl_xor(mx, 16));
      mx = fmaxf(mx, __shfl_xor(mx, 32));
      float s = 0.f, o = 0.f;
      float pb2v = pB2[c];
#pragma unroll
      for (int reg = 0; reg < 4; ++reg) {
        float e_ = expf(lg[reg] - mx);
        s += e_;
        float vv = vb[(size_t)mr[reg] * 128 + c] + pos_[rt][ct][reg] + pb2v;
        o = fmaf(e_, vv, o);
      }
      s += __shfl_xor(s, 16);
      s += __shfl_xor(s, 32);
      o += __shfl_xor(o, 16);
      o += __shfl_xor(o, 32);
      if (lq == 0) outb[(size_t)Q * 128 + c] = o / s;
    }
  }
}

// ---------------- host launch ----------------
extern "C" void kernel_launch(void* const* d_in, const int* in_sizes, int n_in,
                              void* d_out, int out_size, void* d_ws, size_t ws_size,
                              hipStream_t stream) {
  const float* xyz = (const float*)d_in[0];
  const float* feat = (const float*)d_in[1];
  const float* Wq = (const float*)d_in[2];
  const float* Wk = (const float*)d_in[3];
  const float* Wv = (const float*)d_in[4];
  const float* pW1 = (const float*)d_in[5];
  const float* pb1 = (const float*)d_in[6];
  const float* pg = (const float*)d_in[7];
  const float* pbeta = (const float*)d_in[8];
  const float* pmean = (const float*)d_in[9];
  const float* pvar = (const float*)d_in[10];
  const float* pW2 = (const float*)d_in[11];
  const float* pb2 = (const float*)d_in[12];
  const float* aW1 = (const float*)d_in[13];
  const float* ab1 = (const float*)d_in[14];
  const float* ag = (const float*)d_in[15];
  const float* abeta = (const float*)d_in[16];
  const float* amean = (const float*)d_in[17];
  const float* avar = (const float*)d_in[18];
  const float* aW2 = (const float*)d_in[19];
  const float* ab2 = (const float*)d_in[20];
  const float* Wout = (const float*)d_in[21];
  float* out = (float*)d_out;
  char* ws = (char*)d_ws;

  size_t off = 0;
  auto alloc = [&](size_t bytes) {
    size_t r = off;
    off += (bytes + 255) & ~(size_t)255;
    return r;
  };
  float4* xyzw = (float4*)(ws + alloc((size_t)BB * NN * 16));
  int* idx = (int*)(ws + alloc((size_t)BB * NN * KK * 4));
  size_t o_qb = alloc((size_t)BB * NN * CC * 4);
  size_t o_kb = alloc((size_t)BB * NN * CC * 4);
  size_t o_vb = alloc((size_t)BB * NN * CC * 4);
  size_t o_ob = alloc((size_t)BB * NN * CC * 4);
  float* qbA = (float*)(ws + o_qb);
  float* kbA = (float*)(ws + o_kb);
  float* vb = (float*)(ws + o_vb);
  float* outb = (float*)(ws + o_ob);
  // KNN candidate SoA planes (16.8 MB each) alias qbA..outb (dead until knn2 done)
  u32* cand_d = (u32*)(ws + o_qb);
  u32* cand_i = (u32*)(ws + o_vb);
  // folded weights + packed split planes (live whole run)
  float* WqA = (float*)(ws + alloc(128 * 128 * 4));
  float* WkA = (float*)(ws + alloc(128 * 128 * 4));
  float* WpA = (float*)(ws + alloc(128 * 128 * 4));
  float* tvec = (float*)(ws + alloc(128 * 4));
  ushort_t* Phall = (ushort_t*)(ws + alloc(7 * 16384 * 2));
  ushort_t* Plall = (ushort_t*)(ws + alloc(7 * 16384 * 2));

  k_prep<<<(BB * NN) / 256, 256, 0, stream>>>(xyz, xyzw);
  k_fold<<<49, 128, 0, stream>>>(aW1, Wq, Wk, pW2, pb2, WqA, WkA, WpA, tvec);
  // planes: 0=pW2 1=WpA 2=aW2 3=WqA 4=WkA 5=Wv 6=Wout
  k_packw<<<56, 256, 0, stream>>>(pW2, WpA, aW2, WqA, WkA, Wv, Wout, Phall, Plall);

  k_knn1<<<dim3((BB * NN) / 256, CHN), 256, 0, stream>>>(xyzw, cand_d, cand_i);
  k_knn2<<<(BB * NN) / 128, 128, 0, stream>>>(cand_d, cand_i, idx);

  k_mms<3><<<(BB * NN) / 32, 256, 0, stream>>>(feat, Phall, Plall, 3, qbA, kbA, vb);

  k_fused<<<(BB * NN * KK) / 64, 256, 0, stream>>>(
      xyzw, idx, qbA, kbA, vb, pW1, pb1, pg, pbeta, pmean, pvar, pb2, ab1, ag,
      abeta, amean, avar, ab2, tvec, Phall, Plall, outb);

  k_mms<1><<<(BB * NN) / 32, 256, 0, stream>>>(outb, Phall, Plall, 6, out, nullptr,
                                               nullptr);
}

// Round 7
// 378.329 us; speedup vs baseline: 3.5022x; 1.0394x over previous
//
#include <hip/hip_runtime.h>
#include <cstdint>
#include <cstddef>

#define BB 2
#define NN 8192
#define CC 128
#define KK 16
#define CHN 16
#define CHL (NN / CHN)
#define EPSV 1e-5f
#define CAP 24

typedef unsigned long long u64;
typedef unsigned int u32;
typedef unsigned short ushort_t;
typedef short short8v __attribute__((ext_vector_type(8)));
typedef float f32x4 __attribute__((ext_vector_type(4)));

__device__ __forceinline__ float med3f(float x, float y, float z) {
  float r;
  asm("v_med3_f32 %0, %1, %2, %3" : "=v"(r) : "v"(x), "v"(y), "v"(z));
  return r;
}

// ---------------- prep: pack (x,y,z, sq) ----------------
__global__ __launch_bounds__(256) void k_prep(const float* __restrict__ xyz,
                                              float4* __restrict__ xyzw) {
  int t = blockIdx.x * 256 + threadIdx.x;
  if (t >= BB * NN) return;
  float x = xyz[t * 3 + 0], y = xyz[t * 3 + 1], z = xyz[t * 3 + 2];
  float sq = __fadd_rn(__fadd_rn(__fmul_rn(x, x), __fmul_rn(y, y)), __fmul_rn(z, z));
  xyzw[t] = make_float4(x, y, z, sq);
}

// EXACT reference-rounded distance (defines the selected set)
__device__ __forceinline__ float distf(const float4& q, const float4& c) {
  float dot = __fadd_rn(__fadd_rn(__fmul_rn(q.x, c.x), __fmul_rn(q.y, c.y)),
                        __fmul_rn(q.z, c.z));
  float d = __fsub_rn(__fadd_rn(q.w, c.w), __fmul_rn(2.0f, dot));
  return fmaxf(d, 0.0f);
}

// FMA screening distance: p = (-2x,-2y,-2z, sq). |dq - d_exact| <~ 3e-5.
__device__ __forceinline__ float distq(const float4& p, const float4& c) {
  return fmaf(p.z, c.z, fmaf(p.y, c.y, fmaf(p.x, c.x, p.w + c.w)));
}

// exact (dist,idx)-lexicographic merge of collected candidates, then write
__device__ __forceinline__ void merge_write(const float4* __restrict__ pts,
                                            const float4 q, const u32* __restrict__ mybuf,
                                            int cnt, int m0, int ch, int t,
                                            u32* __restrict__ cand_d,
                                            u32* __restrict__ cand_i) {
  double keys[KK];
#pragma unroll
  for (int i = 0; i < KK; ++i) keys[i] = __longlong_as_double(0x7FEFFFFFFFFFFFFFLL);
  if (cnt <= CAP) {
    for (int j = 0; j < cnt; ++j) {
      int m = (int)mybuf[j];
      float d = distf(q, pts[m]);
      u64 kb_ = ((u64)__float_as_uint(d) << 32) | (u32)(m0 + m);
      double kd = __longlong_as_double((long long)kb_);
      if (kd < keys[KK - 1]) {
#pragma unroll
        for (int i = 0; i < KK; ++i) {
          double lo = fmin(keys[i], kd);
          kd = fmax(keys[i], kd);
          keys[i] = lo;
        }
      }
    }
  } else {
    // pathological overflow: exact full rescan (never for random data)
    for (int mi = 0; mi < CHL; ++mi) {
      float d = distf(q, pts[mi]);
      u64 kb_ = ((u64)__float_as_uint(d) << 32) | (u32)(m0 + mi);
      double kd = __longlong_as_double((long long)kb_);
      if (kd < keys[KK - 1]) {
#pragma unroll
        for (int i = 0; i < KK; ++i) {
          double lo = fmin(keys[i], kd);
          kd = fmax(keys[i], kd);
          keys[i] = lo;
        }
      }
    }
  }
#pragma unroll
  for (int j = 0; j < KK; ++j) {
    u64 kk = (u64)__double_as_longlong(keys[j]);
    cand_d[(size_t)(ch * KK + j) * (BB * NN) + t] = (u32)(kk >> 32);
    cand_i[(size_t)(ch * KK + j) * (BB * NN) + t] = (u32)kk;
  }
}

// ---------------- KNN pass 1: 2 queries/thread, fma screen + exact merge ------
__global__ __launch_bounds__(256) void k_knn1(const float4* __restrict__ xyzw,
                                              u32* __restrict__ cand_d,
                                              u32* __restrict__ cand_i) {
  __shared__ float4 pts[CHL];
  __shared__ u32 buf[512 * CAP];
  const int tid = threadIdx.x;
  const int qb = blockIdx.x * 512;  // 512-query span, within one batch
  const int ch = blockIdx.y;
  const int b = qb >> 13;
  const int m0 = ch * CHL;
  for (int i = tid; i < CHL; i += 256) pts[i] = xyzw[b * NN + m0 + i];
  const int n0 = qb + tid, n1 = qb + 256 + tid;
  const float4 qA = xyzw[n0], qB = xyzw[n1];
  const float4 pA = make_float4(-2.f * qA.x, -2.f * qA.y, -2.f * qA.z, qA.w);
  const float4 pB = make_float4(-2.f * qB.x, -2.f * qB.y, -2.f * qB.z, qB.w);
  __syncthreads();

  // phase 1: screened smallest-16 values, two independent med3 ripples
  float a0[KK], a1[KK];
#pragma unroll
  for (int i = 0; i < KK; ++i) {
    a0[i] = 3.4e38f;
    a1[i] = 3.4e38f;
  }
#pragma unroll 2
  for (int mi = 0; mi < CHL; ++mi) {
    const float4 c = pts[mi];
    const float dA = distq(pA, c);
    const float dB = distq(pB, c);
#pragma unroll
    for (int i = KK - 1; i >= 1; --i) a0[i] = med3f(dA, a0[i - 1], a0[i]);
    a0[0] = fminf(dA, a0[0]);
#pragma unroll
    for (int i = KK - 1; i >= 1; --i) a1[i] = med3f(dB, a1[i - 1], a1[i]);
    a1[0] = fminf(dB, a1[0]);
  }
  // certified margin: collected set provably superset of exact top-16
  const float thrA = a0[KK - 1] + (2.5e-4f + 2e-5f * fabsf(a0[KK - 1]));
  const float thrB = a1[KK - 1] + (2.5e-4f + 2e-5f * fabsf(a1[KK - 1]));

  // phase 2: collect chunk-local indices passing the screen
  u32* bufA = &buf[tid * CAP];
  u32* bufB = &buf[(256 + tid) * CAP];
  int cA = 0, cB = 0;
#pragma unroll 2
  for (int mi = 0; mi < CHL; ++mi) {
    const float4 c = pts[mi];
    const float dA = distq(pA, c);
    const float dB = distq(pB, c);
    if (dA <= thrA) {
      if (cA < CAP) bufA[cA] = (u32)mi;
      ++cA;
    }
    if (dB <= thrB) {
      if (cB < CAP) bufB[cB] = (u32)mi;
      ++cB;
    }
  }

  merge_write(pts, qA, bufA, cA, m0, ch, n0, cand_d, cand_i);
  merge_write(pts, qB, bufB, cB, m0, ch, n1, cand_d, cand_i);
}

// ---------------- KNN pass 2 (exact stored dists; unchanged) ----------------
__global__ __launch_bounds__(128) void k_knn2(const u32* __restrict__ cand_d,
                                              const u32* __restrict__ cand_i,
                                              int* __restrict__ idx) {
  const int t = blockIdx.x * 128 + threadIdx.x;
  float a[KK];
#pragma unroll
  for (int i = 0; i < KK; ++i) a[i] = 3.4e38f;
#pragma unroll 4
  for (int i = 0; i < CHN * KK; ++i) {
    float d = __uint_as_float(cand_d[(size_t)i * (BB * NN) + t]);
#pragma unroll
    for (int s = KK - 1; s >= 1; --s) a[s] = med3f(d, a[s - 1], a[s]);
    a[0] = fminf(d, a[0]);
  }
  const float thr = a[KK - 1];
  double keys[KK];
#pragma unroll
  for (int i = 0; i < KK; ++i) keys[i] = __longlong_as_double(0x7FEFFFFFFFFFFFFFLL);
  for (int i = 0; i < CHN * KK; ++i) {
    u32 db = cand_d[(size_t)i * (BB * NN) + t];
    float d = __uint_as_float(db);
    if (d <= thr) {
      u64 kb_ = ((u64)db << 32) | (u64)cand_i[(size_t)i * (BB * NN) + t];
      double kd = __longlong_as_double((long long)kb_);
      if (kd < keys[KK - 1]) {
#pragma unroll
        for (int s = 0; s < KK; ++s) {
          double lo = fmin(keys[s], kd);
          kd = fmax(keys[s], kd);
          keys[s] = lo;
        }
      }
    }
  }
#pragma unroll
  for (int j = 0; j < KK; ++j)
    idx[t * KK + j] = (int)((u64)__double_as_longlong(keys[j]) & 0xffffffffu);
}

// ---------------- weight folding: Wd = aW1 @ Wsrc ----------------
__global__ __launch_bounds__(128) void k_fold(const float* __restrict__ aW1,
                                              const float* __restrict__ Wq,
                                              const float* __restrict__ Wk,
                                              const float* __restrict__ pW2,
                                              const float* __restrict__ pb2,
                                              float* __restrict__ WqA,
                                              float* __restrict__ WkA,
                                              float* __restrict__ WpA,
                                              float* __restrict__ tvec) {
  const int bx = blockIdx.x;
  const int j = threadIdx.x;
  if (bx == 48) {
    float s = 0.f;
    for (int i = 0; i < 128; ++i) s = fmaf(aW1[j * 128 + i], pb2[i], s);
    tvec[j] = s;
    return;
  }
  const int mat = bx >> 4;
  const int c0 = (bx & 15) * 8;
  const float* S = (mat == 0) ? Wq : (mat == 1) ? Wk : pW2;
  float* D = (mat == 0) ? WqA : (mat == 1) ? WkA : WpA;
  float acc[8];
#pragma unroll
  for (int r = 0; r < 8; ++r) acc[r] = 0.f;
  for (int i = 0; i < 128; ++i) {
    float sv = S[i * 128 + j];
#pragma unroll
    for (int r = 0; r < 8; ++r) acc[r] = fmaf(aW1[(c0 + r) * 128 + i], sv, acc[r]);
  }
#pragma unroll
  for (int r = 0; r < 8; ++r) D[(c0 + r) * 128 + j] = acc[r];
}

// ---------------- split-bf16 helpers ----------------
__device__ __forceinline__ void splitf(float a, ushort_t& h, ushort_t& l) {
  u32 ab = __float_as_uint(a);
  h = (ushort_t)(ab >> 16);
  float hif = __uint_as_float(ab & 0xffff0000u);
  l = (ushort_t)(__float_as_uint(a - hif) >> 16);
}

// pack W [128][128] fp32 -> frag-ordered split planes (7 matrices)
__global__ __launch_bounds__(256) void k_packw(
    const float* __restrict__ S0, const float* __restrict__ S1,
    const float* __restrict__ S2, const float* __restrict__ S3,
    const float* __restrict__ S4, const float* __restrict__ S5,
    const float* __restrict__ S6, ushort_t* __restrict__ Phall,
    ushort_t* __restrict__ Plall) {
  const int bx = blockIdx.x;
  const int mat = bx >> 3;
  const int T = bx & 7;
  const float* S;
  switch (mat) {
    case 0: S = S0; break;
    case 1: S = S1; break;
    case 2: S = S2; break;
    case 3: S = S3; break;
    case 4: S = S4; break;
    case 5: S = S5; break;
    default: S = S6; break;
  }
  const int tid = threadIdx.x;
  const int s = tid >> 4;
  const int lr = tid & 15;
  const int c = T * 16 + lr;
  short8v vh, vl;
#pragma unroll
  for (int e = 0; e < 8; ++e) {
    ushort_t hh, ll;
    splitf(S[c * 128 + s * 8 + e], hh, ll);
    vh[e] = (short)hh;
    vl[e] = (short)ll;
  }
  const int po = mat * 16384 + T * 2048 + s * 128 + lr * 8;
  *(short8v*)&Phall[po] = vh;
  *(short8v*)&Plall[po] = vl;
}

// stage R rows x 128 cols fp32 -> hi/lo bf16 planes in LDS, XOR-swizzled
template <int ITERS>
__device__ __forceinline__ void stage_rows(const float4* __restrict__ G4,
                                           ushort_t* Bh, ushort_t* Bl, int tid) {
#pragma unroll
  for (int i = 0; i < ITERS; ++i) {
    int f = i * 256 + tid;
    int r = f >> 5, k4 = f & 31;
    float4 v = G4[f];
    ushort_t h0, l0, h1, l1, h2, l2, h3, l3;
    splitf(v.x, h0, l0);
    splitf(v.y, h1, l1);
    splitf(v.z, h2, l2);
    splitf(v.w, h3, l3);
    int slot = k4 >> 1;
    int sub = (k4 & 1) * 4;
    int base = r * 128 + ((slot ^ (r & 15)) * 8) + sub;
    *(uint2*)&Bh[base] = make_uint2((u32)h0 | ((u32)h1 << 16), (u32)h2 | ((u32)h3 << 16));
    *(uint2*)&Bl[base] = make_uint2((u32)l0 | ((u32)l1 << 16), (u32)l2 | ((u32)l3 << 16));
  }
}

// 64-row LDS-A x GLOBAL-packed-W split GEMM (k_fused)
__device__ __forceinline__ void gemm64g(const ushort_t* ABh, const ushort_t* ABl,
                                        const ushort_t* __restrict__ Ph,
                                        const ushort_t* __restrict__ Pl,
                                        f32x4 acc[2][4], int tid) {
  const int l = tid & 63, wid = tid >> 6;
  const int wrow = wid >> 1, wcol = wid & 1;
  const int lq = l >> 4, lr = l & 15;
#pragma unroll
  for (int ks = 0; ks < 4; ++ks) {
    const int sw8 = (((ks * 4 + lq) ^ lr) * 8);
    short8v ah[2], al[2], wh[4], wl[4];
#pragma unroll
    for (int ct = 0; ct < 4; ++ct) {
      int off = (wcol * 4 + ct) * 2048 + (ks * 4 + lq) * 128 + lr * 8;
      wh[ct] = *(const short8v*)&Ph[off];
      wl[ct] = *(const short8v*)&Pl[off];
    }
#pragma unroll
    for (int rt = 0; rt < 2; ++rt) {
      int row = wrow * 32 + rt * 16 + lr;
      ah[rt] = *(const short8v*)&ABh[row * 128 + sw8];
      al[rt] = *(const short8v*)&ABl[row * 128 + sw8];
    }
    __builtin_amdgcn_s_setprio(1);
#pragma unroll
    for (int rt = 0; rt < 2; ++rt)
#pragma unroll
      for (int ct = 0; ct < 4; ++ct) {
        acc[rt][ct] = __builtin_amdgcn_mfma_f32_16x16x32_bf16(ah[rt], wh[ct], acc[rt][ct], 0, 0, 0);
        acc[rt][ct] = __builtin_amdgcn_mfma_f32_16x16x32_bf16(ah[rt], wl[ct], acc[rt][ct], 0, 0, 0);
        acc[rt][ct] = __builtin_amdgcn_mfma_f32_16x16x32_bf16(al[rt], wh[ct], acc[rt][ct], 0, 0, 0);
      }
    __builtin_amdgcn_s_setprio(0);
  }
}

// ---------------- 32-row GEMM, W streamed from packed planes ----------------
template <int NW>
__global__ __launch_bounds__(256) void k_mms(const float* __restrict__ A,
                                             const ushort_t* __restrict__ Phall,
                                             const ushort_t* __restrict__ Plall,
                                             int m0, float* __restrict__ C0,
                                             float* __restrict__ C1,
                                             float* __restrict__ C2) {
  __shared__ ushort_t ABh[32 * 128], ABl[32 * 128];
  const int tid = threadIdx.x;
  const int Rbase = blockIdx.x * 32;
  stage_rows<4>((const float4*)(A + (size_t)Rbase * 128), ABh, ABl, tid);
  __syncthreads();
  const int l = tid & 63, wid = tid >> 6;
  const int lq = l >> 4, lr = l & 15;
  float* Cs[3] = {C0, C1, C2};
#pragma unroll
  for (int w = 0; w < NW; ++w) {
    const ushort_t* Ph = Phall + (size_t)(m0 + w) * 16384;
    const ushort_t* Pl = Plall + (size_t)(m0 + w) * 16384;
    f32x4 acc[2][2];
#pragma unroll
    for (int rt = 0; rt < 2; ++rt)
#pragma unroll
      for (int ct = 0; ct < 2; ++ct) acc[rt][ct] = (f32x4)0.f;
#pragma unroll
    for (int ks = 0; ks < 4; ++ks) {
      const int sw8 = (((ks * 4 + lq) ^ lr) * 8);
      short8v ah[2], al[2], wh[2], wl[2];
#pragma unroll
      for (int ct = 0; ct < 2; ++ct) {
        int off = (wid * 2 + ct) * 2048 + (ks * 4 + lq) * 128 + lr * 8;
        wh[ct] = *(const short8v*)&Ph[off];
        wl[ct] = *(const short8v*)&Pl[off];
      }
#pragma unroll
      for (int rt = 0; rt < 2; ++rt) {
        int row = rt * 16 + lr;
        ah[rt] = *(const short8v*)&ABh[row * 128 + sw8];
        al[rt] = *(const short8v*)&ABl[row * 128 + sw8];
      }
#pragma unroll
      for (int rt = 0; rt < 2; ++rt)
#pragma unroll
        for (int ct = 0; ct < 2; ++ct) {
          acc[rt][ct] = __builtin_amdgcn_mfma_f32_16x16x32_bf16(ah[rt], wh[ct], acc[rt][ct], 0, 0, 0);
          acc[rt][ct] = __builtin_amdgcn_mfma_f32_16x16x32_bf16(ah[rt], wl[ct], acc[rt][ct], 0, 0, 0);
          acc[rt][ct] = __builtin_amdgcn_mfma_f32_16x16x32_bf16(al[rt], wh[ct], acc[rt][ct], 0, 0, 0);
        }
    }
#pragma unroll
    for (int rt = 0; rt < 2; ++rt)
#pragma unroll
      for (int ct = 0; ct < 2; ++ct) {
        int c = (wid * 2 + ct) * 16 + lr;
#pragma unroll
        for (int reg = 0; reg < 4; ++reg) {
          int R = Rbase + rt * 16 + lq * 4 + reg;
          Cs[w][(size_t)R * 128 + c] = acc[rt][ct][reg];
        }
      }
  }
}

// ---------------- fused chain (64 rows / 4 queries per block) ----------------
__global__ __launch_bounds__(256, 3) void k_fused(
    const float4* __restrict__ xyzw, const int* __restrict__ idx,
    const float* __restrict__ qbA, const float* __restrict__ kbA,
    const float* __restrict__ vb, const float* __restrict__ pW1,
    const float* __restrict__ pb1, const float* __restrict__ pg,
    const float* __restrict__ pbeta, const float* __restrict__ pm,
    const float* __restrict__ pv, const float* __restrict__ pb2,
    const float* __restrict__ ab1, const float* __restrict__ ag,
    const float* __restrict__ abeta, const float* __restrict__ am,
    const float* __restrict__ av, const float* __restrict__ ab2,
    const float* __restrict__ tvec, const ushort_t* __restrict__ Phall,
    const ushort_t* __restrict__ Plall, float* __restrict__ outb) {
  __shared__ ushort_t ABh[64 * 128], ABl[64 * 128];
  __shared__ float4 fW1[128];
  __shared__ float sA[128], tA[128], pB2[128], aB2[128];
  __shared__ int idxs[64];
  const int tid = threadIdx.x;
  const int Qbase = blockIdx.x * 4;
  const int b = Qbase >> 13;

  if (tid < 64) idxs[tid] = idx[Qbase * KK + tid];
  if (tid < 128) {
    int c = tid;
    float s1 = pg[c] / sqrtf(pv[c] + EPSV);
    fW1[c] = make_float4(pW1[c * 3] * s1, pW1[c * 3 + 1] * s1, pW1[c * 3 + 2] * s1,
                         (pb1[c] - pm[c]) * s1 + pbeta[c]);
    float s2 = ag[c] / sqrtf(av[c] + EPSV);
    sA[c] = s2;
    tA[c] = fmaf(s2, ab1[c] + tvec[c] - am[c], abeta[c]);
    pB2[c] = pb2[c];
    aB2[c] = ab2[c];
  }
  __syncthreads();

  // h1 tile (64 rows) -> A planes
  {
    int r = tid >> 2, qq = tid & 3;
    int Q = Qbase + (r >> 4);
    int m = idxs[r];
    float4 pq = xyzw[Q];
    float4 pn = xyzw[b * NN + m];
    float rx = pn.x - pq.x, ry = pn.y - pq.y, rz = pn.z - pq.z;
#pragma unroll
    for (int g = 0; g < 4; ++g) {
      short8v vh, vl;
      int c0 = qq * 32 + g * 8;
#pragma unroll
      for (int e = 0; e < 8; ++e) {
        float4 w = fW1[c0 + e];
        float h = fmaxf(fmaf(rz, w.z, fmaf(ry, w.y, fmaf(rx, w.x, w.w))), 0.f);
        ushort_t hh, ll;
        splitf(h, hh, ll);
        vh[e] = (short)hh;
        vl[e] = (short)ll;
      }
      int sw = (c0 >> 3) ^ (r & 15);
      *(short8v*)&ABh[r * 128 + sw * 8] = vh;
      *(short8v*)&ABl[r * 128 + sw * 8] = vl;
    }
  }
  __syncthreads();

  const int l = tid & 63, wid = tid >> 6;
  const int wrow = wid >> 1, wcol = wid & 1;
  const int lq = l >> 4, lr = l & 15;

  // GEMM0a: pos = h1 @ pW2^T (held); GEMM0b: posA = h1 @ WpA^T (held)
  f32x4 pos_[2][4], pa_[2][4];
#pragma unroll
  for (int rt = 0; rt < 2; ++rt)
#pragma unroll
    for (int ct = 0; ct < 4; ++ct) {
      pos_[rt][ct] = (f32x4)0.f;
      pa_[rt][ct] = (f32x4)0.f;
    }
  gemm64g(ABh, ABl, Phall, Plall, pos_, tid);
  gemm64g(ABh, ABl, Phall + 16384, Plall + 16384, pa_, tid);
  __syncthreads();

  // z = relu(s * (qA_gather - kA_gather + posA) + t) -> A planes
#pragma unroll
  for (int rt = 0; rt < 2; ++rt) {
    int qi_loc = wrow * 2 + rt;
    int Q = Qbase + qi_loc;
    int mr[4];
#pragma unroll
    for (int reg = 0; reg < 4; ++reg) mr[reg] = b * NN + idxs[qi_loc * 16 + lq * 4 + reg];
#pragma unroll
    for (int ct = 0; ct < 4; ++ct) {
      int c = wcol * 64 + ct * 16 + lr;
      float qv = qbA[(size_t)Q * 128 + c];
      float sc = sA[c], tc = tA[c];
#pragma unroll
      for (int reg = 0; reg < 4; ++reg) {
        float u = qv - kbA[(size_t)mr[reg] * 128 + c] + pa_[rt][ct][reg];
        float z = fmaxf(fmaf(u, sc, tc), 0.f);
        ushort_t hh, ll;
        splitf(z, hh, ll);
        int R15 = lq * 4 + reg;
        int row = wrow * 32 + rt * 16 + R15;
        int base = row * 128 + (((c >> 3) ^ R15) * 8) + (c & 7);
        ABh[base] = hh;
        ABl[base] = ll;
      }
    }
  }
  __syncthreads();

  // GEMM2: logits = z @ aW2^T (+ab2); softmax over 16 neighbors; combine
  f32x4 acc[2][4];
#pragma unroll
  for (int rt = 0; rt < 2; ++rt)
#pragma unroll
    for (int ct = 0; ct < 4; ++ct) acc[rt][ct] = (f32x4)0.f;
  gemm64g(ABh, ABl, Phall + 32768, Plall + 32768, acc, tid);

#pragma unroll
  for (int rt = 0; rt < 2; ++rt) {
    int qi_loc = wrow * 2 + rt;
    int Q = Qbase + qi_loc;
    int mr[4];
#pragma unroll
    for (int reg = 0; reg < 4; ++reg) mr[reg] = b * NN + idxs[qi_loc * 16 + lq * 4 + reg];
#pragma unroll
    for (int ct = 0; ct < 4; ++ct) {
      int c = wcol * 64 + ct * 16 + lr;
      float ab2v = aB2[c];
      float lg[4];
#pragma unroll
      for (int reg = 0; reg < 4; ++reg) lg[reg] = acc[rt][ct][reg] + ab2v;
      float mx = fmaxf(fmaxf(lg[0], lg[1]), fmaxf(lg[2], lg[3]));
      mx = fmaxf(mx, __shfl_xor(mx, 16));
      mx = fmaxf(mx, __shfl_xor(mx, 32));
      float s = 0.f, o = 0.f;
      float pb2v = pB2[c];
#pragma unroll
      for (int reg = 0; reg < 4; ++reg) {
        float e_ = expf(lg[reg] - mx);
        s += e_;
        float vv = vb[(size_t)mr[reg] * 128 + c] + pos_[rt][ct][reg] + pb2v;
        o = fmaf(e_, vv, o);
      }
      s += __shfl_xor(s, 16);
      s += __shfl_xor(s, 32);
      o += __shfl_xor(o, 16);
      o += __shfl_xor(o, 32);
      if (lq == 0) outb[(size_t)Q * 128 + c] = o / s;
    }
  }
}

// ---------------- host launch ----------------
extern "C" void kernel_launch(void* const* d_in, const int* in_sizes, int n_in,
                              void* d_out, int out_size, void* d_ws, size_t ws_size,
                              hipStream_t stream) {
  const float* xyz = (const float*)d_in[0];
  const float* feat = (const float*)d_in[1];
  const float* Wq = (const float*)d_in[2];
  const float* Wk = (const float*)d_in[3];
  const float* Wv = (const float*)d_in[4];
  const float* pW1 = (const float*)d_in[5];
  const float* pb1 = (const float*)d_in[6];
  const float* pg = (const float*)d_in[7];
  const float* pbeta = (const float*)d_in[8];
  const float* pmean = (const float*)d_in[9];
  const float* pvar = (const float*)d_in[10];
  const float* pW2 = (const float*)d_in[11];
  const float* pb2 = (const float*)d_in[12];
  const float* aW1 = (const float*)d_in[13];
  const float* ab1 = (const float*)d_in[14];
  const float* ag = (const float*)d_in[15];
  const float* abeta = (const float*)d_in[16];
  const float* amean = (const float*)d_in[17];
  const float* avar = (const float*)d_in[18];
  const float* aW2 = (const float*)d_in[19];
  const float* ab2 = (const float*)d_in[20];
  const float* Wout = (const float*)d_in[21];
  float* out = (float*)d_out;
  char* ws = (char*)d_ws;

  size_t off = 0;
  auto alloc = [&](size_t bytes) {
    size_t r = off;
    off += (bytes + 255) & ~(size_t)255;
    return r;
  };
  float4* xyzw = (float4*)(ws + alloc((size_t)BB * NN * 16));
  int* idx = (int*)(ws + alloc((size_t)BB * NN * KK * 4));
  size_t o_qb = alloc((size_t)BB * NN * CC * 4);
  size_t o_kb = alloc((size_t)BB * NN * CC * 4);
  size_t o_vb = alloc((size_t)BB * NN * CC * 4);
  size_t o_ob = alloc((size_t)BB * NN * CC * 4);
  float* qbA = (float*)(ws + o_qb);
  float* kbA = (float*)(ws + o_kb);
  float* vb = (float*)(ws + o_vb);
  float* outb = (float*)(ws + o_ob);
  // KNN candidate SoA planes (16.8 MB each) alias qbA..outb (dead until knn2 done)
  u32* cand_d = (u32*)(ws + o_qb);
  u32* cand_i = (u32*)(ws + o_vb);
  // folded weights + packed split planes (live whole run)
  float* WqA = (float*)(ws + alloc(128 * 128 * 4));
  float* WkA = (float*)(ws + alloc(128 * 128 * 4));
  float* WpA = (float*)(ws + alloc(128 * 128 * 4));
  float* tvec = (float*)(ws + alloc(128 * 4));
  ushort_t* Phall = (ushort_t*)(ws + alloc(7 * 16384 * 2));
  ushort_t* Plall = (ushort_t*)(ws + alloc(7 * 16384 * 2));

  k_prep<<<(BB * NN) / 256, 256, 0, stream>>>(xyz, xyzw);
  k_fold<<<49, 128, 0, stream>>>(aW1, Wq, Wk, pW2, pb2, WqA, WkA, WpA, tvec);
  // planes: 0=pW2 1=WpA 2=aW2 3=WqA 4=WkA 5=Wv 6=Wout
  k_packw<<<56, 256, 0, stream>>>(pW2, WpA, aW2, WqA, WkA, Wv, Wout, Phall, Plall);

  k_knn1<<<dim3((BB * NN) / 512, CHN), 256, 0, stream>>>(xyzw, cand_d, cand_i);
  k_knn2<<<(BB * NN) / 128, 128, 0, stream>>>(cand_d, cand_i, idx);

  k_mms<3><<<(BB * NN) / 32, 256, 0, stream>>>(feat, Phall, Plall, 3, qbA, kbA, vb);

  k_fused<<<(BB * NN * KK) / 64, 256, 0, stream>>>(
      xyzw, idx, qbA, kbA, vb, pW1, pb1, pg, pbeta, pmean, pvar, pb2, ab1, ag,
      abeta, amean, avar, ab2, tvec, Phall, Plall, outb);

  k_mms<1><<<(BB * NN) / 32, 256, 0, stream>>>(outb, Phall, Plall, 6, out, nullptr,
                                               nullptr);
}